// Round 1
// baseline (6293.211 us; speedup 1.0000x reference)
//
#include <hip/hip_runtime.h>
#include <math.h>

#define NN 50000
#define EE 800000
#define HH 64
#define NBASIS 8
#define NLAYER 2
#define NGRAPH 64

__device__ __forceinline__ float silu_f(float v) {
    return v * (1.0f / (1.0f + __expf(-v)));
}

// x[n][j] = embed[z[n]][j]
__global__ __launch_bounds__(256) void embed_gather_k(
    const int* __restrict__ z, const float* __restrict__ embed,
    float* __restrict__ x)
{
    int idx = blockIdx.x * 256 + threadIdx.x;
    if (idx >= NN * HH) return;
    int n = idx >> 6;
    int j = idx & 63;
    x[idx] = embed[(z[n] << 6) + j];
}

// One thread per edge. msg_in = [x[col] (64), x[row] (64), edge_attr (8)]
// h = silu(msg_in @ w1 + b1); m = h @ w2 + b2; atomicAdd into agg[col].
__global__ __launch_bounds__(256) void msg_k(
    const float* __restrict__ pos,
    const int* __restrict__ erow, const int* __restrict__ ecol,
    const float* __restrict__ x,
    const float* __restrict__ w1, const float* __restrict__ b1,
    const float* __restrict__ w2, const float* __restrict__ b2,
    float* __restrict__ agg)
{
    int e = blockIdx.x * 256 + threadIdx.x;
    if (e >= EE) return;
    int r = erow[e], c = ecol[e];

    float dx = pos[3*r]   - pos[3*c];
    float dy = pos[3*r+1] - pos[3*c+1];
    float dz = pos[3*r+2] - pos[3*c+2];
    float d = sqrtf(dx*dx + dy*dy + dz*dz);
    float env = 0.0f;
    if (d < 5.0f) {
        float cv = __cosf(d * 0.31415926535897932f);  // pi/(2*CUTOFF)
        env = cv * cv;
    }
    float scale = (d > 0.0f) ? (env / d) : env;
    float ea[NBASIS];
#pragma unroll
    for (int k = 0; k < NBASIS; ++k)
        ea[k] = __sinf((float)(k + 1) * 0.62831853071795865f * d) * scale;  // pi/CUTOFF

    float h[HH];
#pragma unroll
    for (int j = 0; j < HH; ++j) h[j] = b1[j];

    // segment 1: x[col] -> rows 0..63 of w1
    {
        const float4* xi = (const float4*)(x + ((size_t)c << 6));
        for (int i4 = 0; i4 < 16; ++i4) {
            float4 v = xi[i4];
            const float* w = w1 + i4 * 4 * HH;
#pragma unroll
            for (int j = 0; j < HH; ++j) h[j] = fmaf(v.x, w[j], h[j]);
#pragma unroll
            for (int j = 0; j < HH; ++j) h[j] = fmaf(v.y, w[HH + j], h[j]);
#pragma unroll
            for (int j = 0; j < HH; ++j) h[j] = fmaf(v.z, w[2*HH + j], h[j]);
#pragma unroll
            for (int j = 0; j < HH; ++j) h[j] = fmaf(v.w, w[3*HH + j], h[j]);
        }
    }
    // segment 2: x[row] -> rows 64..127 of w1
    {
        const float4* xj = (const float4*)(x + ((size_t)r << 6));
        for (int i4 = 0; i4 < 16; ++i4) {
            float4 v = xj[i4];
            const float* w = w1 + (64 + i4 * 4) * HH;
#pragma unroll
            for (int j = 0; j < HH; ++j) h[j] = fmaf(v.x, w[j], h[j]);
#pragma unroll
            for (int j = 0; j < HH; ++j) h[j] = fmaf(v.y, w[HH + j], h[j]);
#pragma unroll
            for (int j = 0; j < HH; ++j) h[j] = fmaf(v.z, w[2*HH + j], h[j]);
#pragma unroll
            for (int j = 0; j < HH; ++j) h[j] = fmaf(v.w, w[3*HH + j], h[j]);
        }
    }
    // segment 3: edge_attr -> rows 128..135 of w1
#pragma unroll
    for (int k = 0; k < NBASIS; ++k) {
        const float* w = w1 + (128 + k) * HH;
        float v = ea[k];
#pragma unroll
        for (int j = 0; j < HH; ++j) h[j] = fmaf(v, w[j], h[j]);
    }

#pragma unroll
    for (int k = 0; k < HH; ++k) h[k] = silu_f(h[k]);

    float out[HH];
#pragma unroll
    for (int j = 0; j < HH; ++j) out[j] = b2[j];
#pragma unroll
    for (int k = 0; k < HH; ++k) {
        float hv = h[k];
        const float* w = w2 + k * HH;
#pragma unroll
        for (int j = 0; j < HH; ++j) out[j] = fmaf(hv, w[j], out[j]);
    }

    float* ar = agg + ((size_t)c << 6);
#pragma unroll
    for (int j = 0; j < HH; ++j) atomicAdd(ar + j, out[j]);
}

// One thread per node. u_in = [x (64), agg (64)]; x += silu(u_in@w1+b1)@w2+b2
__global__ __launch_bounds__(256) void upd_k(
    float* __restrict__ x, const float* __restrict__ agg,
    const float* __restrict__ w1, const float* __restrict__ b1,
    const float* __restrict__ w2, const float* __restrict__ b2)
{
    int n = blockIdx.x * 256 + threadIdx.x;
    if (n >= NN) return;

    float h[HH];
#pragma unroll
    for (int j = 0; j < HH; ++j) h[j] = b1[j];

    {
        const float4* xi = (const float4*)(x + ((size_t)n << 6));
        for (int i4 = 0; i4 < 16; ++i4) {
            float4 v = xi[i4];
            const float* w = w1 + i4 * 4 * HH;
#pragma unroll
            for (int j = 0; j < HH; ++j) h[j] = fmaf(v.x, w[j], h[j]);
#pragma unroll
            for (int j = 0; j < HH; ++j) h[j] = fmaf(v.y, w[HH + j], h[j]);
#pragma unroll
            for (int j = 0; j < HH; ++j) h[j] = fmaf(v.z, w[2*HH + j], h[j]);
#pragma unroll
            for (int j = 0; j < HH; ++j) h[j] = fmaf(v.w, w[3*HH + j], h[j]);
        }
    }
    {
        const float4* ai = (const float4*)(agg + ((size_t)n << 6));
        for (int i4 = 0; i4 < 16; ++i4) {
            float4 v = ai[i4];
            const float* w = w1 + (64 + i4 * 4) * HH;
#pragma unroll
            for (int j = 0; j < HH; ++j) h[j] = fmaf(v.x, w[j], h[j]);
#pragma unroll
            for (int j = 0; j < HH; ++j) h[j] = fmaf(v.y, w[HH + j], h[j]);
#pragma unroll
            for (int j = 0; j < HH; ++j) h[j] = fmaf(v.z, w[2*HH + j], h[j]);
#pragma unroll
            for (int j = 0; j < HH; ++j) h[j] = fmaf(v.w, w[3*HH + j], h[j]);
        }
    }

#pragma unroll
    for (int k = 0; k < HH; ++k) h[k] = silu_f(h[k]);

    float out[HH];
#pragma unroll
    for (int j = 0; j < HH; ++j) out[j] = b2[j];
#pragma unroll
    for (int k = 0; k < HH; ++k) {
        float hv = h[k];
        const float* w = w2 + k * HH;
#pragma unroll
        for (int j = 0; j < HH; ++j) out[j] = fmaf(hv, w[j], out[j]);
    }

    float* xr = x + ((size_t)n << 6);
#pragma unroll
    for (int j = 0; j < HH; ++j) xr[j] = xr[j] + out[j];
}

// One thread per node: atomic_e = silu(x@w1+b1)@w2 + b2; energy[batch[n]] += e
__global__ __launch_bounds__(256) void head_k(
    const float* __restrict__ x,
    const float* __restrict__ w1, const float* __restrict__ b1,
    const float* __restrict__ w2, const float* __restrict__ b2,
    const int* __restrict__ batch, float* __restrict__ energy)
{
    int n = blockIdx.x * 256 + threadIdx.x;
    if (n >= NN) return;

    float h[HH];
#pragma unroll
    for (int j = 0; j < HH; ++j) h[j] = b1[j];

    const float4* xi = (const float4*)(x + ((size_t)n << 6));
    for (int i4 = 0; i4 < 16; ++i4) {
        float4 v = xi[i4];
        const float* w = w1 + i4 * 4 * HH;
#pragma unroll
        for (int j = 0; j < HH; ++j) h[j] = fmaf(v.x, w[j], h[j]);
#pragma unroll
        for (int j = 0; j < HH; ++j) h[j] = fmaf(v.y, w[HH + j], h[j]);
#pragma unroll
        for (int j = 0; j < HH; ++j) h[j] = fmaf(v.z, w[2*HH + j], h[j]);
#pragma unroll
        for (int j = 0; j < HH; ++j) h[j] = fmaf(v.w, w[3*HH + j], h[j]);
    }

    float e = b2[0];
#pragma unroll
    for (int k = 0; k < HH; ++k) e = fmaf(silu_f(h[k]), w2[k], e);

    atomicAdd(energy + batch[n], e);
}

extern "C" void kernel_launch(void* const* d_in, const int* in_sizes, int n_in,
                              void* d_out, int out_size, void* d_ws, size_t ws_size,
                              hipStream_t stream) {
    const int*   z       = (const int*)  d_in[0];
    const float* pos     = (const float*)d_in[1];
    const int*   eidx    = (const int*)  d_in[2];
    const int*   batch   = (const int*)  d_in[3];
    const float* embed   = (const float*)d_in[4];
    const float* msg_w1  = (const float*)d_in[5];   // (NL, 136, 64)
    const float* msg_b1  = (const float*)d_in[6];   // (NL, 64)
    const float* msg_w2  = (const float*)d_in[7];   // (NL, 64, 64)
    const float* msg_b2  = (const float*)d_in[8];   // (NL, 64)
    const float* upd_w1  = (const float*)d_in[9];   // (NL, 128, 64)
    const float* upd_b1  = (const float*)d_in[10];  // (NL, 64)
    const float* upd_w2  = (const float*)d_in[11];  // (NL, 64, 64)
    const float* upd_b2  = (const float*)d_in[12];  // (NL, 64)
    const float* eh_w1   = (const float*)d_in[13];  // (64, 64)
    const float* eh_b1   = (const float*)d_in[14];  // (64,)
    const float* eh_w2   = (const float*)d_in[15];  // (64, 1)
    const float* eh_b2   = (const float*)d_in[16];  // (1,)

    const int* erow = eidx;
    const int* ecol = eidx + EE;

    float* x   = (float*)d_ws;                       // NN*HH floats (12.8 MB)
    float* agg = x + (size_t)NN * HH;                // NN*HH floats (12.8 MB)
    float* energy = (float*)d_out;

    hipMemsetAsync(energy, 0, NGRAPH * sizeof(float), stream);

    embed_gather_k<<<(NN * HH + 255) / 256, 256, 0, stream>>>(z, embed, x);

    for (int l = 0; l < NLAYER; ++l) {
        hipMemsetAsync(agg, 0, (size_t)NN * HH * sizeof(float), stream);
        msg_k<<<(EE + 255) / 256, 256, 0, stream>>>(
            pos, erow, ecol, x,
            msg_w1 + (size_t)l * (2*HH + NBASIS) * HH,
            msg_b1 + (size_t)l * HH,
            msg_w2 + (size_t)l * HH * HH,
            msg_b2 + (size_t)l * HH,
            agg);
        upd_k<<<(NN + 255) / 256, 256, 0, stream>>>(
            x, agg,
            upd_w1 + (size_t)l * 2*HH * HH,
            upd_b1 + (size_t)l * HH,
            upd_w2 + (size_t)l * HH * HH,
            upd_b2 + (size_t)l * HH);
    }

    head_k<<<(NN + 255) / 256, 256, 0, stream>>>(
        x, eh_w1, eh_b1, eh_w2, eh_b2, batch, energy);
}

// Round 2
// 1930.273 us; speedup vs baseline: 3.2603x; 3.2603x over previous
//
#include <hip/hip_runtime.h>
#include <math.h>

#define NN 50000
#define EE 800000
#define HH 64
#define NBASIS 8
#define NLAYER 2
#define NGRAPH 64

__device__ __forceinline__ float silu_f(float v) {
    return v * (1.0f / (1.0f + __expf(-v)));
}

// x[n][j] = embed[z[n]][j]
__global__ __launch_bounds__(256) void embed_gather_k(
    const int* __restrict__ z, const float* __restrict__ embed,
    float* __restrict__ x)
{
    int idx = blockIdx.x * 256 + threadIdx.x;
    if (idx >= NN * HH) return;
    int n = idx >> 6;
    int j = idx & 63;
    x[idx] = embed[(z[n] << 6) + j];
}

// ---- CSR build (once per launch; graph identical across layers) ----
__global__ __launch_bounds__(256) void deg_k(
    const int* __restrict__ ecol, int* __restrict__ deg)
{
    int e = blockIdx.x * 256 + threadIdx.x;
    if (e < EE) atomicAdd(&deg[ecol[e]], 1);
}

// single-block exclusive scan over deg[NN] -> start, cursor
__global__ __launch_bounds__(1024) void scan_k(
    const int* __restrict__ deg, int* __restrict__ start,
    int* __restrict__ cursor)
{
    __shared__ int wsum[16];
    __shared__ int carry_s;
    int lane = threadIdx.x & 63;
    int wave = threadIdx.x >> 6;
    if (threadIdx.x == 0) carry_s = 0;
    __syncthreads();
    for (int base = 0; base < NN; base += 1024) {
        int i = base + (int)threadIdx.x;
        int v = (i < NN) ? deg[i] : 0;
        int s = v;  // inclusive wave scan
#pragma unroll
        for (int off = 1; off < 64; off <<= 1) {
            int t = __shfl_up(s, off, 64);
            if (lane >= off) s += t;
        }
        if (lane == 63) wsum[wave] = s;
        __syncthreads();
        if (wave == 0) {
            int ws = (lane < 16) ? wsum[lane] : 0;
            int ss = ws;
#pragma unroll
            for (int off = 1; off < 16; off <<= 1) {
                int t = __shfl_up(ss, off, 64);
                if (lane >= off) ss += t;
            }
            if (lane < 16) wsum[lane] = ss - ws;  // exclusive wave offset
        }
        __syncthreads();
        int carry = carry_s;
        int excl = carry + wsum[wave] + (s - v);
        if (i < NN) { start[i] = excl; cursor[i] = excl; }
        __syncthreads();
        if (threadIdx.x == 1023) carry_s = excl + v;
        __syncthreads();
    }
}

__global__ __launch_bounds__(256) void scatter_k(
    const int* __restrict__ ecol, int* __restrict__ cursor,
    int* __restrict__ perm)
{
    int e = blockIdx.x * 256 + threadIdx.x;
    if (e < EE) {
        int slot = atomicAdd(&cursor[ecol[e]], 1);
        perm[slot] = e;
    }
}

// One thread per SORTED slot s; edge e = perm[s]. After computing the
// 64-float message, wave-level segmented suffix-reduction keyed by col,
// then one atomic vector per segment head (~12x fewer atomics).
__global__ __launch_bounds__(256) void msg_k(
    const float* __restrict__ pos,
    const int* __restrict__ erow, const int* __restrict__ ecol,
    const int* __restrict__ perm,
    const float* __restrict__ x,
    const float* __restrict__ w1, const float* __restrict__ b1,
    const float* __restrict__ w2, const float* __restrict__ b2,
    float* __restrict__ agg)
{
    int s = blockIdx.x * 256 + threadIdx.x;
    if (s >= EE) return;
    int e = perm[s];
    int r = erow[e], c = ecol[e];

    float dx = pos[3*r]   - pos[3*c];
    float dy = pos[3*r+1] - pos[3*c+1];
    float dz = pos[3*r+2] - pos[3*c+2];
    float d = sqrtf(dx*dx + dy*dy + dz*dz);
    float env = 0.0f;
    if (d < 5.0f) {
        float cv = __cosf(d * 0.31415926535897932f);  // pi/(2*CUTOFF)
        env = cv * cv;
    }
    float scale = (d > 0.0f) ? (env / d) : env;
    float ea[NBASIS];
#pragma unroll
    for (int k = 0; k < NBASIS; ++k)
        ea[k] = __sinf((float)(k + 1) * 0.62831853071795865f * d) * scale;  // pi/CUTOFF

    float h[HH];
#pragma unroll
    for (int j = 0; j < HH; ++j) h[j] = b1[j];

    // segment 1: x[col] -> rows 0..63 of w1
    {
        const float4* xi = (const float4*)(x + ((size_t)c << 6));
        for (int i4 = 0; i4 < 16; ++i4) {
            float4 v = xi[i4];
            const float* w = w1 + i4 * 4 * HH;
#pragma unroll
            for (int j = 0; j < HH; ++j) h[j] = fmaf(v.x, w[j], h[j]);
#pragma unroll
            for (int j = 0; j < HH; ++j) h[j] = fmaf(v.y, w[HH + j], h[j]);
#pragma unroll
            for (int j = 0; j < HH; ++j) h[j] = fmaf(v.z, w[2*HH + j], h[j]);
#pragma unroll
            for (int j = 0; j < HH; ++j) h[j] = fmaf(v.w, w[3*HH + j], h[j]);
        }
    }
    // segment 2: x[row] -> rows 64..127 of w1
    {
        const float4* xj = (const float4*)(x + ((size_t)r << 6));
        for (int i4 = 0; i4 < 16; ++i4) {
            float4 v = xj[i4];
            const float* w = w1 + (64 + i4 * 4) * HH;
#pragma unroll
            for (int j = 0; j < HH; ++j) h[j] = fmaf(v.x, w[j], h[j]);
#pragma unroll
            for (int j = 0; j < HH; ++j) h[j] = fmaf(v.y, w[HH + j], h[j]);
#pragma unroll
            for (int j = 0; j < HH; ++j) h[j] = fmaf(v.z, w[2*HH + j], h[j]);
#pragma unroll
            for (int j = 0; j < HH; ++j) h[j] = fmaf(v.w, w[3*HH + j], h[j]);
        }
    }
    // segment 3: edge_attr -> rows 128..135 of w1
#pragma unroll
    for (int k = 0; k < NBASIS; ++k) {
        const float* w = w1 + (128 + k) * HH;
        float v = ea[k];
#pragma unroll
        for (int j = 0; j < HH; ++j) h[j] = fmaf(v, w[j], h[j]);
    }

#pragma unroll
    for (int k = 0; k < HH; ++k) h[k] = silu_f(h[k]);

    float out[HH];
#pragma unroll
    for (int j = 0; j < HH; ++j) out[j] = b2[j];
#pragma unroll
    for (int k = 0; k < HH; ++k) {
        float hv = h[k];
        const float* w = w2 + k * HH;
#pragma unroll
        for (int j = 0; j < HH; ++j) out[j] = fmaf(hv, w[j], out[j]);
    }

    // ---- wave segmented suffix reduction keyed by c (edges sorted by c) ----
    int lane = threadIdx.x & 63;
#pragma unroll
    for (int off = 1; off < 64; off <<= 1) {
        int nc = __shfl_down(c, off, 64);
        bool take = ((lane + off) < 64) && (nc == c);
#pragma unroll
        for (int j = 0; j < HH; ++j) {
            float nv = __shfl_down(out[j], off, 64);
            out[j] += take ? nv : 0.0f;
        }
    }
    int pc = __shfl_up(c, 1, 64);
    bool head = (lane == 0) || (pc != c);
    if (head) {
        float* ar = agg + ((size_t)c << 6);
#pragma unroll
        for (int j = 0; j < HH; ++j) atomicAdd(ar + j, out[j]);
    }
}

// One thread per node. u_in = [x (64), agg (64)]; x += silu(u_in@w1+b1)@w2+b2
__global__ __launch_bounds__(256) void upd_k(
    float* __restrict__ x, const float* __restrict__ agg,
    const float* __restrict__ w1, const float* __restrict__ b1,
    const float* __restrict__ w2, const float* __restrict__ b2)
{
    int n = blockIdx.x * 256 + threadIdx.x;
    if (n >= NN) return;

    float h[HH];
#pragma unroll
    for (int j = 0; j < HH; ++j) h[j] = b1[j];

    {
        const float4* xi = (const float4*)(x + ((size_t)n << 6));
        for (int i4 = 0; i4 < 16; ++i4) {
            float4 v = xi[i4];
            const float* w = w1 + i4 * 4 * HH;
#pragma unroll
            for (int j = 0; j < HH; ++j) h[j] = fmaf(v.x, w[j], h[j]);
#pragma unroll
            for (int j = 0; j < HH; ++j) h[j] = fmaf(v.y, w[HH + j], h[j]);
#pragma unroll
            for (int j = 0; j < HH; ++j) h[j] = fmaf(v.z, w[2*HH + j], h[j]);
#pragma unroll
            for (int j = 0; j < HH; ++j) h[j] = fmaf(v.w, w[3*HH + j], h[j]);
        }
    }
    {
        const float4* ai = (const float4*)(agg + ((size_t)n << 6));
        for (int i4 = 0; i4 < 16; ++i4) {
            float4 v = ai[i4];
            const float* w = w1 + (64 + i4 * 4) * HH;
#pragma unroll
            for (int j = 0; j < HH; ++j) h[j] = fmaf(v.x, w[j], h[j]);
#pragma unroll
            for (int j = 0; j < HH; ++j) h[j] = fmaf(v.y, w[HH + j], h[j]);
#pragma unroll
            for (int j = 0; j < HH; ++j) h[j] = fmaf(v.z, w[2*HH + j], h[j]);
#pragma unroll
            for (int j = 0; j < HH; ++j) h[j] = fmaf(v.w, w[3*HH + j], h[j]);
        }
    }

#pragma unroll
    for (int k = 0; k < HH; ++k) h[k] = silu_f(h[k]);

    float out[HH];
#pragma unroll
    for (int j = 0; j < HH; ++j) out[j] = b2[j];
#pragma unroll
    for (int k = 0; k < HH; ++k) {
        float hv = h[k];
        const float* w = w2 + k * HH;
#pragma unroll
        for (int j = 0; j < HH; ++j) out[j] = fmaf(hv, w[j], out[j]);
    }

    float* xr = x + ((size_t)n << 6);
#pragma unroll
    for (int j = 0; j < HH; ++j) xr[j] = xr[j] + out[j];
}

// One thread per node: atomic_e = silu(x@w1+b1)@w2 + b2; energy[batch[n]] += e
__global__ __launch_bounds__(256) void head_k(
    const float* __restrict__ x,
    const float* __restrict__ w1, const float* __restrict__ b1,
    const float* __restrict__ w2, const float* __restrict__ b2,
    const int* __restrict__ batch, float* __restrict__ energy)
{
    int n = blockIdx.x * 256 + threadIdx.x;
    if (n >= NN) return;

    float h[HH];
#pragma unroll
    for (int j = 0; j < HH; ++j) h[j] = b1[j];

    const float4* xi = (const float4*)(x + ((size_t)n << 6));
    for (int i4 = 0; i4 < 16; ++i4) {
        float4 v = xi[i4];
        const float* w = w1 + i4 * 4 * HH;
#pragma unroll
        for (int j = 0; j < HH; ++j) h[j] = fmaf(v.x, w[j], h[j]);
#pragma unroll
        for (int j = 0; j < HH; ++j) h[j] = fmaf(v.y, w[HH + j], h[j]);
#pragma unroll
        for (int j = 0; j < HH; ++j) h[j] = fmaf(v.z, w[2*HH + j], h[j]);
#pragma unroll
        for (int j = 0; j < HH; ++j) h[j] = fmaf(v.w, w[3*HH + j], h[j]);
    }

    float e = b2[0];
#pragma unroll
    for (int k = 0; k < HH; ++k) e = fmaf(silu_f(h[k]), w2[k], e);

    atomicAdd(energy + batch[n], e);
}

extern "C" void kernel_launch(void* const* d_in, const int* in_sizes, int n_in,
                              void* d_out, int out_size, void* d_ws, size_t ws_size,
                              hipStream_t stream) {
    const int*   z       = (const int*)  d_in[0];
    const float* pos     = (const float*)d_in[1];
    const int*   eidx    = (const int*)  d_in[2];
    const int*   batch   = (const int*)  d_in[3];
    const float* embed   = (const float*)d_in[4];
    const float* msg_w1  = (const float*)d_in[5];   // (NL, 136, 64)
    const float* msg_b1  = (const float*)d_in[6];   // (NL, 64)
    const float* msg_w2  = (const float*)d_in[7];   // (NL, 64, 64)
    const float* msg_b2  = (const float*)d_in[8];   // (NL, 64)
    const float* upd_w1  = (const float*)d_in[9];   // (NL, 128, 64)
    const float* upd_b1  = (const float*)d_in[10];  // (NL, 64)
    const float* upd_w2  = (const float*)d_in[11];  // (NL, 64, 64)
    const float* upd_b2  = (const float*)d_in[12];  // (NL, 64)
    const float* eh_w1   = (const float*)d_in[13];  // (64, 64)
    const float* eh_b1   = (const float*)d_in[14];  // (64,)
    const float* eh_w2   = (const float*)d_in[15];  // (64, 1)
    const float* eh_b2   = (const float*)d_in[16];  // (1,)

    const int* erow = eidx;
    const int* ecol = eidx + EE;

    // ws layout
    float* x      = (float*)d_ws;                       // NN*HH
    float* agg    = x + (size_t)NN * HH;                // NN*HH
    int*   deg    = (int*)(agg + (size_t)NN * HH);      // NN
    int*   start  = deg + NN;                           // NN
    int*   cursor = start + NN;                         // NN
    int*   perm   = cursor + NN;                        // EE
    float* energy = (float*)d_out;

    hipMemsetAsync(energy, 0, NGRAPH * sizeof(float), stream);
    hipMemsetAsync(deg, 0, NN * sizeof(int), stream);

    embed_gather_k<<<(NN * HH + 255) / 256, 256, 0, stream>>>(z, embed, x);

    // build CSR permutation (edges sorted by col) once
    deg_k<<<(EE + 255) / 256, 256, 0, stream>>>(ecol, deg);
    scan_k<<<1, 1024, 0, stream>>>(deg, start, cursor);
    scatter_k<<<(EE + 255) / 256, 256, 0, stream>>>(ecol, cursor, perm);

    for (int l = 0; l < NLAYER; ++l) {
        hipMemsetAsync(agg, 0, (size_t)NN * HH * sizeof(float), stream);
        msg_k<<<(EE + 255) / 256, 256, 0, stream>>>(
            pos, erow, ecol, perm, x,
            msg_w1 + (size_t)l * (2*HH + NBASIS) * HH,
            msg_b1 + (size_t)l * HH,
            msg_w2 + (size_t)l * HH * HH,
            msg_b2 + (size_t)l * HH,
            agg);
        upd_k<<<(NN + 255) / 256, 256, 0, stream>>>(
            x, agg,
            upd_w1 + (size_t)l * 2*HH * HH,
            upd_b1 + (size_t)l * HH,
            upd_w2 + (size_t)l * HH * HH,
            upd_b2 + (size_t)l * HH);
    }

    head_k<<<(NN + 255) / 256, 256, 0, stream>>>(
        x, eh_w1, eh_b1, eh_w2, eh_b2, batch, energy);
}

// Round 4
// 1562.216 us; speedup vs baseline: 4.0284x; 1.2356x over previous
//
#include <hip/hip_runtime.h>
#include <math.h>

#define NN 50000
#define EE 800000
#define HH 64
#define NBASIS 8
#define NLAYER 2
#define NGRAPH 64
#define NBLK1 49  // ceil(NN/1024)

// derive the packed-half vector type from the builtin itself so all uses agree
using half2_t = decltype(__builtin_amdgcn_cvt_pkrtz(0.0f, 0.0f));

__device__ __forceinline__ float silu_f(float v) {
    return v * (1.0f / (1.0f + __expf(-v)));
}

__device__ __forceinline__ half2_t u2h(unsigned u) {
    union { unsigned u; half2_t h; } x; x.u = u; return x.h;
}

__device__ __forceinline__ unsigned pk2(float a, float b) {
    union { half2_t h; unsigned u; } x;
    x.h = __builtin_amdgcn_cvt_pkrtz(a, b);
    return x.u;
}

// gather embed -> x (fp32) and x_h (f16 pairs). idx over NN*32 pairs.
__global__ __launch_bounds__(256) void embed_gather_k(
    const int* __restrict__ z, const float* __restrict__ embed,
    float* __restrict__ x, unsigned* __restrict__ xh)
{
    int idx = blockIdx.x * 256 + threadIdx.x;
    if (idx >= NN * 32) return;
    int n = idx >> 5;
    int p = idx & 31;
    const float2* er = (const float2*)(embed + ((size_t)z[n] << 6));
    float2 v = er[p];
    ((float2*)x)[idx] = v;
    xh[idx] = pk2(v.x, v.y);
}

// ---- weight prepack (f16 pairs along k) ----
__global__ __launch_bounds__(256) void pack_w1_k(
    const float* __restrict__ msg_w1, unsigned* __restrict__ wp1)
{
    int idx = blockIdx.x * 256 + threadIdx.x;
    if (idx >= NLAYER * 68 * 64) return;
    int l = idx / (68 * 64);
    int rem = idx - l * 68 * 64;
    int p = rem >> 6, j = rem & 63;
    const float* w = msg_w1 + (size_t)l * 136 * 64;
    wp1[idx] = pk2(w[(2 * p) * 64 + j], w[(2 * p + 1) * 64 + j]);
}

__global__ __launch_bounds__(256) void pack_w2_k(
    const float* __restrict__ msg_w2, unsigned* __restrict__ wp2)
{
    int idx = blockIdx.x * 256 + threadIdx.x;
    if (idx >= NLAYER * 32 * 64) return;
    int l = idx / (32 * 64);
    int rem = idx - l * 32 * 64;
    int p = rem >> 6, j = rem & 63;
    const float* w = msg_w2 + (size_t)l * 64 * 64;
    wp2[idx] = pk2(w[(2 * p) * 64 + j], w[(2 * p + 1) * 64 + j]);
}

// ---- CSR build ----
__global__ __launch_bounds__(256) void deg_k(
    const int* __restrict__ ecol, int* __restrict__ deg)
{
    int e = blockIdx.x * 256 + threadIdx.x;
    if (e < EE) atomicAdd(&deg[ecol[e]], 1);
}

// phase 1: per-block (1024) exclusive scan, block totals to bsum
__global__ __launch_bounds__(1024) void scan1_k(
    const int* __restrict__ deg, int* __restrict__ cursor,
    int* __restrict__ bsum)
{
    __shared__ int wsum[16];
    int t = threadIdx.x, lane = t & 63, wave = t >> 6;
    int i = blockIdx.x * 1024 + t;
    int v = (i < NN) ? deg[i] : 0;
    int s = v;
#pragma unroll
    for (int off = 1; off < 64; off <<= 1) {
        int tv = __shfl_up(s, off, 64);
        if (lane >= off) s += tv;
    }
    if (lane == 63) wsum[wave] = s;
    __syncthreads();
    if (wave == 0) {
        int ws = (lane < 16) ? wsum[lane] : 0;
        int ss = ws;
#pragma unroll
        for (int off = 1; off < 16; off <<= 1) {
            int tv = __shfl_up(ss, off, 64);
            if (lane >= off) ss += tv;
        }
        if (lane < 16) wsum[lane] = ss - ws;
    }
    __syncthreads();
    int excl = wsum[wave] + s - v;
    if (i < NN) cursor[i] = excl;
    if (t == 1023) bsum[blockIdx.x] = excl + v;
}

// phase 2: single wave scans the 49 block sums in place (exclusive)
__global__ __launch_bounds__(64) void scan2_k(int* __restrict__ bsum)
{
    int lane = threadIdx.x;
    int v = (lane < NBLK1) ? bsum[lane] : 0;
    int s = v;
#pragma unroll
    for (int off = 1; off < 64; off <<= 1) {
        int tv = __shfl_up(s, off, 64);
        if (lane >= off) s += tv;
    }
    if (lane < NBLK1) bsum[lane] = s - v;
}

// phase 3: add block offsets
__global__ __launch_bounds__(256) void scan3_k(
    int* __restrict__ cursor, const int* __restrict__ bsum)
{
    int i = blockIdx.x * 256 + threadIdx.x;
    if (i < NN) cursor[i] += bsum[i >> 10];
}

__global__ __launch_bounds__(256) void scatter_k(
    const int* __restrict__ ecol, int* __restrict__ cursor,
    int* __restrict__ perm)
{
    int e = blockIdx.x * 256 + threadIdx.x;
    if (e < EE) {
        int slot = atomicAdd(&cursor[ecol[e]], 1);
        perm[slot] = e;
    }
}

// One thread per SORTED slot; f16 dot2 MLP; wave segmented reduce; atomics.
__global__ __launch_bounds__(256) void msg_k(
    const float* __restrict__ pos,
    const int* __restrict__ erow, const int* __restrict__ ecol,
    const int* __restrict__ perm,
    const unsigned* __restrict__ xh,
    const unsigned* __restrict__ wp1, const float* __restrict__ b1,
    const unsigned* __restrict__ wp2, const float* __restrict__ b2,
    float* __restrict__ agg)
{
    int s = blockIdx.x * 256 + threadIdx.x;
    if (s >= EE) return;
    int e = perm[s];
    int r = erow[e], c = ecol[e];

    float dx = pos[3*r]   - pos[3*c];
    float dy = pos[3*r+1] - pos[3*c+1];
    float dz = pos[3*r+2] - pos[3*c+2];
    float d = sqrtf(dx*dx + dy*dy + dz*dz);
    float env = 0.0f;
    if (d < 5.0f) {
        float cv = __cosf(d * 0.31415926535897932f);  // pi/(2*CUTOFF)
        env = cv * cv;
    }
    float scale = (d > 0.0f) ? (env / d) : env;
    float ea[NBASIS];
#pragma unroll
    for (int k = 0; k < NBASIS; ++k)
        ea[k] = __sinf((float)(k + 1) * 0.62831853071795865f * d) * scale;  // pi/CUTOFF
    unsigned eap[4];
#pragma unroll
    for (int q = 0; q < 4; ++q) eap[q] = pk2(ea[2*q], ea[2*q+1]);

    float h[HH];
#pragma unroll
    for (int j = 0; j < HH; ++j) h[j] = b1[j];

    // layer 1: x[col] pairs 0..31, x[row] pairs 32..63, ea pairs 64..67
    {
        const uint4* xc4 = (const uint4*)(xh + ((size_t)c << 5));
        for (int i4 = 0; i4 < 8; ++i4) {
            uint4 xv = xc4[i4];
            unsigned xs[4] = {xv.x, xv.y, xv.z, xv.w};
#pragma unroll
            for (int q = 0; q < 4; ++q) {
                half2_t a = u2h(xs[q]);
                const unsigned* wr = wp1 + (size_t)(i4 * 4 + q) * 64;
#pragma unroll
                for (int j = 0; j < HH; ++j)
                    h[j] = __builtin_amdgcn_fdot2(a, u2h(wr[j]), h[j], false);
            }
        }
    }
    {
        const uint4* xr4 = (const uint4*)(xh + ((size_t)r << 5));
        for (int i4 = 0; i4 < 8; ++i4) {
            uint4 xv = xr4[i4];
            unsigned xs[4] = {xv.x, xv.y, xv.z, xv.w};
#pragma unroll
            for (int q = 0; q < 4; ++q) {
                half2_t a = u2h(xs[q]);
                const unsigned* wr = wp1 + (size_t)(32 + i4 * 4 + q) * 64;
#pragma unroll
                for (int j = 0; j < HH; ++j)
                    h[j] = __builtin_amdgcn_fdot2(a, u2h(wr[j]), h[j], false);
            }
        }
    }
#pragma unroll
    for (int q = 0; q < 4; ++q) {
        half2_t a = u2h(eap[q]);
        const unsigned* wr = wp1 + (size_t)(64 + q) * 64;
#pragma unroll
        for (int j = 0; j < HH; ++j)
            h[j] = __builtin_amdgcn_fdot2(a, u2h(wr[j]), h[j], false);
    }

    // silu + pack to f16 pairs
    unsigned hp[32];
#pragma unroll
    for (int p = 0; p < 32; ++p)
        hp[p] = pk2(silu_f(h[2*p]), silu_f(h[2*p+1]));

    float out[HH];
#pragma unroll
    for (int j = 0; j < HH; ++j) out[j] = b2[j];
    for (int p = 0; p < 32; ++p) {
        half2_t a = u2h(hp[p]);
        const unsigned* wr = wp2 + (size_t)p * 64;
#pragma unroll
        for (int j = 0; j < HH; ++j)
            out[j] = __builtin_amdgcn_fdot2(a, u2h(wr[j]), out[j], false);
    }

    // ---- wave segmented suffix reduction keyed by c (edges sorted by c) ----
    int lane = threadIdx.x & 63;
#pragma unroll
    for (int off = 1; off < 64; off <<= 1) {
        int nc = __shfl_down(c, off, 64);
        bool take = ((lane + off) < 64) && (nc == c);
#pragma unroll
        for (int j = 0; j < HH; ++j) {
            float nv = __shfl_down(out[j], off, 64);
            out[j] += take ? nv : 0.0f;
        }
    }
    int pc = __shfl_up(c, 1, 64);
    bool head = (lane == 0) || (pc != c);
    if (head) {
        float* ar = agg + ((size_t)c << 6);
#pragma unroll
        for (int j = 0; j < HH; ++j) atomicAdd(ar + j, out[j]);
    }
}

// One thread per node. u_in = [x (64), agg (64)]; x += silu(u_in@w1+b1)@w2+b2
// Also refreshes x_h (f16).
__global__ __launch_bounds__(256) void upd_k(
    float* __restrict__ x, unsigned* __restrict__ xh,
    const float* __restrict__ agg,
    const float* __restrict__ w1, const float* __restrict__ b1,
    const float* __restrict__ w2, const float* __restrict__ b2)
{
    int n = blockIdx.x * 256 + threadIdx.x;
    if (n >= NN) return;

    float h[HH];
#pragma unroll
    for (int j = 0; j < HH; ++j) h[j] = b1[j];

    {
        const float4* xi = (const float4*)(x + ((size_t)n << 6));
        for (int i4 = 0; i4 < 16; ++i4) {
            float4 v = xi[i4];
            const float* w = w1 + i4 * 4 * HH;
#pragma unroll
            for (int j = 0; j < HH; ++j) h[j] = fmaf(v.x, w[j], h[j]);
#pragma unroll
            for (int j = 0; j < HH; ++j) h[j] = fmaf(v.y, w[HH + j], h[j]);
#pragma unroll
            for (int j = 0; j < HH; ++j) h[j] = fmaf(v.z, w[2*HH + j], h[j]);
#pragma unroll
            for (int j = 0; j < HH; ++j) h[j] = fmaf(v.w, w[3*HH + j], h[j]);
        }
    }
    {
        const float4* ai = (const float4*)(agg + ((size_t)n << 6));
        for (int i4 = 0; i4 < 16; ++i4) {
            float4 v = ai[i4];
            const float* w = w1 + (64 + i4 * 4) * HH;
#pragma unroll
            for (int j = 0; j < HH; ++j) h[j] = fmaf(v.x, w[j], h[j]);
#pragma unroll
            for (int j = 0; j < HH; ++j) h[j] = fmaf(v.y, w[HH + j], h[j]);
#pragma unroll
            for (int j = 0; j < HH; ++j) h[j] = fmaf(v.z, w[2*HH + j], h[j]);
#pragma unroll
            for (int j = 0; j < HH; ++j) h[j] = fmaf(v.w, w[3*HH + j], h[j]);
        }
    }

#pragma unroll
    for (int k = 0; k < HH; ++k) h[k] = silu_f(h[k]);

    float out[HH];
#pragma unroll
    for (int j = 0; j < HH; ++j) out[j] = b2[j];
#pragma unroll
    for (int k = 0; k < HH; ++k) {
        float hv = h[k];
        const float* w = w2 + k * HH;
#pragma unroll
        for (int j = 0; j < HH; ++j) out[j] = fmaf(hv, w[j], out[j]);
    }

    float* xr = x + ((size_t)n << 6);
    unsigned* xhp = xh + ((size_t)n << 5);
#pragma unroll
    for (int p = 0; p < 32; ++p) {
        float v0 = xr[2*p]   + out[2*p];
        float v1 = xr[2*p+1] + out[2*p+1];
        xr[2*p] = v0; xr[2*p+1] = v1;
        xhp[p] = pk2(v0, v1);
    }
}

// One thread per node: atomic_e = silu(x@w1+b1)@w2 + b2; energy[batch[n]] += e
__global__ __launch_bounds__(256) void head_k(
    const float* __restrict__ x,
    const float* __restrict__ w1, const float* __restrict__ b1,
    const float* __restrict__ w2, const float* __restrict__ b2,
    const int* __restrict__ batch, float* __restrict__ energy)
{
    int n = blockIdx.x * 256 + threadIdx.x;
    if (n >= NN) return;

    float h[HH];
#pragma unroll
    for (int j = 0; j < HH; ++j) h[j] = b1[j];

    const float4* xi = (const float4*)(x + ((size_t)n << 6));
    for (int i4 = 0; i4 < 16; ++i4) {
        float4 v = xi[i4];
        const float* w = w1 + i4 * 4 * HH;
#pragma unroll
        for (int j = 0; j < HH; ++j) h[j] = fmaf(v.x, w[j], h[j]);
#pragma unroll
        for (int j = 0; j < HH; ++j) h[j] = fmaf(v.y, w[HH + j], h[j]);
#pragma unroll
        for (int j = 0; j < HH; ++j) h[j] = fmaf(v.z, w[2*HH + j], h[j]);
#pragma unroll
        for (int j = 0; j < HH; ++j) h[j] = fmaf(v.w, w[3*HH + j], h[j]);
    }

    float e = b2[0];
#pragma unroll
    for (int k = 0; k < HH; ++k) e = fmaf(silu_f(h[k]), w2[k], e);

    atomicAdd(energy + batch[n], e);
}

extern "C" void kernel_launch(void* const* d_in, const int* in_sizes, int n_in,
                              void* d_out, int out_size, void* d_ws, size_t ws_size,
                              hipStream_t stream) {
    const int*   z       = (const int*)  d_in[0];
    const float* pos     = (const float*)d_in[1];
    const int*   eidx    = (const int*)  d_in[2];
    const int*   batch   = (const int*)  d_in[3];
    const float* embed   = (const float*)d_in[4];
    const float* msg_w1  = (const float*)d_in[5];   // (NL, 136, 64)
    const float* msg_b1  = (const float*)d_in[6];   // (NL, 64)
    const float* msg_w2  = (const float*)d_in[7];   // (NL, 64, 64)
    const float* msg_b2  = (const float*)d_in[8];   // (NL, 64)
    const float* upd_w1  = (const float*)d_in[9];   // (NL, 128, 64)
    const float* upd_b1  = (const float*)d_in[10];  // (NL, 64)
    const float* upd_w2  = (const float*)d_in[11];  // (NL, 64, 64)
    const float* upd_b2  = (const float*)d_in[12];  // (NL, 64)
    const float* eh_w1   = (const float*)d_in[13];  // (64, 64)
    const float* eh_b1   = (const float*)d_in[14];  // (64,)
    const float* eh_w2   = (const float*)d_in[15];  // (64, 1)
    const float* eh_b2   = (const float*)d_in[16];  // (1,)

    const int* erow = eidx;
    const int* ecol = eidx + EE;

    // ws layout (4-byte units)
    float*    x      = (float*)d_ws;                      // NN*64
    float*    agg    = x + (size_t)NN * HH;               // NN*64
    unsigned* xh     = (unsigned*)(agg + (size_t)NN * HH);// NN*32
    int*      deg    = (int*)(xh + (size_t)NN * 32);      // NN
    int*      cursor = deg + NN;                          // NN
    int*      bsum   = cursor + NN;                       // 64
    int*      perm   = bsum + 64;                         // EE
    unsigned* wp1    = (unsigned*)(perm + EE);            // NL*68*64
    unsigned* wp2    = wp1 + NLAYER * 68 * 64;            // NL*32*64
    float*    energy = (float*)d_out;

    (void)hipMemsetAsync(energy, 0, NGRAPH * sizeof(float), stream);
    (void)hipMemsetAsync(deg, 0, NN * sizeof(int), stream);

    embed_gather_k<<<(NN * 32 + 255) / 256, 256, 0, stream>>>(z, embed, x, xh);
    pack_w1_k<<<(NLAYER * 68 * 64 + 255) / 256, 256, 0, stream>>>(msg_w1, wp1);
    pack_w2_k<<<(NLAYER * 32 * 64 + 255) / 256, 256, 0, stream>>>(msg_w2, wp2);

    // CSR permutation (edges sorted by col)
    deg_k<<<(EE + 255) / 256, 256, 0, stream>>>(ecol, deg);
    scan1_k<<<NBLK1, 1024, 0, stream>>>(deg, cursor, bsum);
    scan2_k<<<1, 64, 0, stream>>>(bsum);
    scan3_k<<<(NN + 255) / 256, 256, 0, stream>>>(cursor, bsum);
    scatter_k<<<(EE + 255) / 256, 256, 0, stream>>>(ecol, cursor, perm);

    for (int l = 0; l < NLAYER; ++l) {
        (void)hipMemsetAsync(agg, 0, (size_t)NN * HH * sizeof(float), stream);
        msg_k<<<(EE + 255) / 256, 256, 0, stream>>>(
            pos, erow, ecol, perm, xh,
            wp1 + (size_t)l * 68 * 64,
            msg_b1 + (size_t)l * HH,
            wp2 + (size_t)l * 32 * 64,
            msg_b2 + (size_t)l * HH,
            agg);
        upd_k<<<(NN + 255) / 256, 256, 0, stream>>>(
            x, xh, agg,
            upd_w1 + (size_t)l * 2*HH * HH,
            upd_b1 + (size_t)l * HH,
            upd_w2 + (size_t)l * HH * HH,
            upd_b2 + (size_t)l * HH);
    }

    head_k<<<(NN + 255) / 256, 256, 0, stream>>>(
        x, eh_w1, eh_b1, eh_w2, eh_b2, batch, energy);
}

// Round 5
// 1559.475 us; speedup vs baseline: 4.0355x; 1.0018x over previous
//
#include <hip/hip_runtime.h>
#include <math.h>

#define NN 50000
#define EE 800000
#define HH 64
#define NBASIS 8
#define NLAYER 2
#define NGRAPH 64
#define NBLK1 49  // ceil(NN/1024)

// derive the packed-half vector type from the builtin itself so all uses agree
using half2_t = decltype(__builtin_amdgcn_cvt_pkrtz(0.0f, 0.0f));

__device__ __forceinline__ float silu_f(float v) {
    return v * (1.0f / (1.0f + __expf(-v)));
}

__device__ __forceinline__ half2_t u2h(unsigned u) {
    union { unsigned u; half2_t h; } x; x.u = u; return x.h;
}

__device__ __forceinline__ unsigned pk2(float a, float b) {
    union { half2_t h; unsigned u; } x;
    x.h = __builtin_amdgcn_cvt_pkrtz(a, b);
    return x.u;
}

// gather embed -> x (fp32) and x_h (f16 pairs). idx over NN*32 pairs.
__global__ __launch_bounds__(256) void embed_gather_k(
    const int* __restrict__ z, const float* __restrict__ embed,
    float* __restrict__ x, unsigned* __restrict__ xh)
{
    int idx = blockIdx.x * 256 + threadIdx.x;
    if (idx >= NN * 32) return;
    int n = idx >> 5;
    int p = idx & 31;
    const float2* er = (const float2*)(embed + ((size_t)z[n] << 6));
    float2 v = er[p];
    ((float2*)x)[idx] = v;
    xh[idx] = pk2(v.x, v.y);
}

// ---- weight prepack (f16 pairs along k) ----
__global__ __launch_bounds__(256) void pack_w1_k(
    const float* __restrict__ msg_w1, unsigned* __restrict__ wp1)
{
    int idx = blockIdx.x * 256 + threadIdx.x;
    if (idx >= NLAYER * 68 * 64) return;
    int l = idx / (68 * 64);
    int rem = idx - l * 68 * 64;
    int p = rem >> 6, j = rem & 63;
    const float* w = msg_w1 + (size_t)l * 136 * 64;
    wp1[idx] = pk2(w[(2 * p) * 64 + j], w[(2 * p + 1) * 64 + j]);
}

__global__ __launch_bounds__(256) void pack_w2_k(
    const float* __restrict__ msg_w2, unsigned* __restrict__ wp2)
{
    int idx = blockIdx.x * 256 + threadIdx.x;
    if (idx >= NLAYER * 32 * 64) return;
    int l = idx / (32 * 64);
    int rem = idx - l * 32 * 64;
    int p = rem >> 6, j = rem & 63;
    const float* w = msg_w2 + (size_t)l * 64 * 64;
    wp2[idx] = pk2(w[(2 * p) * 64 + j], w[(2 * p + 1) * 64 + j]);
}

// ---- CSR build ----
__global__ __launch_bounds__(256) void deg_k(
    const int* __restrict__ ecol, int* __restrict__ deg)
{
    int e = blockIdx.x * 256 + threadIdx.x;
    if (e < EE) atomicAdd(&deg[ecol[e]], 1);
}

// phase 1: per-block (1024) exclusive scan, block totals to bsum
__global__ __launch_bounds__(1024) void scan1_k(
    const int* __restrict__ deg, int* __restrict__ cursor,
    int* __restrict__ bsum)
{
    __shared__ int wsum[16];
    int t = threadIdx.x, lane = t & 63, wave = t >> 6;
    int i = blockIdx.x * 1024 + t;
    int v = (i < NN) ? deg[i] : 0;
    int s = v;
#pragma unroll
    for (int off = 1; off < 64; off <<= 1) {
        int tv = __shfl_up(s, off, 64);
        if (lane >= off) s += tv;
    }
    if (lane == 63) wsum[wave] = s;
    __syncthreads();
    if (wave == 0) {
        int ws = (lane < 16) ? wsum[lane] : 0;
        int ss = ws;
#pragma unroll
        for (int off = 1; off < 16; off <<= 1) {
            int tv = __shfl_up(ss, off, 64);
            if (lane >= off) ss += tv;
        }
        if (lane < 16) wsum[lane] = ss - ws;
    }
    __syncthreads();
    int excl = wsum[wave] + s - v;
    if (i < NN) cursor[i] = excl;
    if (t == 1023) bsum[blockIdx.x] = excl + v;
}

// phase 2: single wave scans the 49 block sums in place (exclusive)
__global__ __launch_bounds__(64) void scan2_k(int* __restrict__ bsum)
{
    int lane = threadIdx.x;
    int v = (lane < NBLK1) ? bsum[lane] : 0;
    int s = v;
#pragma unroll
    for (int off = 1; off < 64; off <<= 1) {
        int tv = __shfl_up(s, off, 64);
        if (lane >= off) s += tv;
    }
    if (lane < NBLK1) bsum[lane] = s - v;
}

// phase 3: add block offsets
__global__ __launch_bounds__(256) void scan3_k(
    int* __restrict__ cursor, const int* __restrict__ bsum)
{
    int i = blockIdx.x * 256 + threadIdx.x;
    if (i < NN) cursor[i] += bsum[i >> 10];
}

__global__ __launch_bounds__(256) void scatter_k(
    const int* __restrict__ ecol, int* __restrict__ cursor,
    int* __restrict__ perm)
{
    int e = blockIdx.x * 256 + threadIdx.x;
    if (e < EE) {
        int slot = atomicAdd(&cursor[ecol[e]], 1);
        perm[slot] = e;
    }
}

// One thread per SORTED slot; f16 dot2 MLP with LDS-staged weights;
// wave segmented reduce; atomics. Grid is exactly EE/256 blocks.
__global__ __launch_bounds__(256) void msg_k(
    const float* __restrict__ pos,
    const int* __restrict__ erow, const int* __restrict__ ecol,
    const int* __restrict__ perm,
    const unsigned* __restrict__ xh,
    const unsigned* __restrict__ wp1, const float* __restrict__ b1,
    const unsigned* __restrict__ wp2, const float* __restrict__ b2,
    float* __restrict__ agg)
{
    __shared__ unsigned w1s[68 * 64];  // 17408 B
    __shared__ unsigned w2s[32 * 64];  //  8192 B
    for (int i = threadIdx.x; i < 68 * 64; i += 256) w1s[i] = wp1[i];
    for (int i = threadIdx.x; i < 32 * 64; i += 256) w2s[i] = wp2[i];
    __syncthreads();

    int s = blockIdx.x * 256 + threadIdx.x;   // EE % 256 == 0: always valid
    int e = perm[s];
    int r = erow[e], c = ecol[e];

    // prefetch gathers into registers (two batches of 8 x uint4)
    uint4 xc[8], xr[8];
    {
        const uint4* xc4 = (const uint4*)(xh + ((size_t)c << 5));
        const uint4* xr4 = (const uint4*)(xh + ((size_t)r << 5));
#pragma unroll
        for (int i4 = 0; i4 < 8; ++i4) xc[i4] = xc4[i4];
#pragma unroll
        for (int i4 = 0; i4 < 8; ++i4) xr[i4] = xr4[i4];
    }

    float dx = pos[3*r]   - pos[3*c];
    float dy = pos[3*r+1] - pos[3*c+1];
    float dz = pos[3*r+2] - pos[3*c+2];
    float d = sqrtf(dx*dx + dy*dy + dz*dz);
    float env = 0.0f;
    if (d < 5.0f) {
        float cv = __cosf(d * 0.31415926535897932f);  // pi/(2*CUTOFF)
        env = cv * cv;
    }
    float scale = (d > 0.0f) ? (env / d) : env;
    float ea[NBASIS];
#pragma unroll
    for (int k = 0; k < NBASIS; ++k)
        ea[k] = __sinf((float)(k + 1) * 0.62831853071795865f * d) * scale;  // pi/CUTOFF
    unsigned eap[4];
#pragma unroll
    for (int q = 0; q < 4; ++q) eap[q] = pk2(ea[2*q], ea[2*q+1]);

    float h[HH];
#pragma unroll
    for (int j = 0; j < HH; ++j) h[j] = b1[j];

    // layer 1: x[col] pairs 0..31, x[row] pairs 32..63, ea pairs 64..67
    for (int i4 = 0; i4 < 8; ++i4) {
        unsigned xs[4] = {xc[i4].x, xc[i4].y, xc[i4].z, xc[i4].w};
#pragma unroll
        for (int q = 0; q < 4; ++q) {
            half2_t a = u2h(xs[q]);
            const unsigned* wr = w1s + (i4 * 4 + q) * 64;
#pragma unroll
            for (int j = 0; j < HH; ++j)
                h[j] = __builtin_amdgcn_fdot2(a, u2h(wr[j]), h[j], false);
        }
    }
    for (int i4 = 0; i4 < 8; ++i4) {
        unsigned xs[4] = {xr[i4].x, xr[i4].y, xr[i4].z, xr[i4].w};
#pragma unroll
        for (int q = 0; q < 4; ++q) {
            half2_t a = u2h(xs[q]);
            const unsigned* wr = w1s + (32 + i4 * 4 + q) * 64;
#pragma unroll
            for (int j = 0; j < HH; ++j)
                h[j] = __builtin_amdgcn_fdot2(a, u2h(wr[j]), h[j], false);
        }
    }
#pragma unroll
    for (int q = 0; q < 4; ++q) {
        half2_t a = u2h(eap[q]);
        const unsigned* wr = w1s + (64 + q) * 64;
#pragma unroll
        for (int j = 0; j < HH; ++j)
            h[j] = __builtin_amdgcn_fdot2(a, u2h(wr[j]), h[j], false);
    }

    // silu + pack to f16 pairs
    unsigned hp[32];
#pragma unroll
    for (int p = 0; p < 32; ++p)
        hp[p] = pk2(silu_f(h[2*p]), silu_f(h[2*p+1]));

    float out[HH];
#pragma unroll
    for (int j = 0; j < HH; ++j) out[j] = b2[j];
    for (int p = 0; p < 32; ++p) {
        half2_t a = u2h(hp[p]);
        const unsigned* wr = w2s + p * 64;
#pragma unroll
        for (int j = 0; j < HH; ++j)
            out[j] = __builtin_amdgcn_fdot2(a, u2h(wr[j]), out[j], false);
    }

    // ---- wave segmented suffix reduction keyed by c (edges sorted by c) ----
    int lane = threadIdx.x & 63;
#pragma unroll
    for (int off = 1; off < 64; off <<= 1) {
        int nc = __shfl_down(c, off, 64);
        bool take = ((lane + off) < 64) && (nc == c);
#pragma unroll
        for (int j = 0; j < HH; ++j) {
            float nv = __shfl_down(out[j], off, 64);
            out[j] += take ? nv : 0.0f;
        }
    }
    int pc = __shfl_up(c, 1, 64);
    bool head = (lane == 0) || (pc != c);
    if (head) {
        float* ar = agg + ((size_t)c << 6);
#pragma unroll
        for (int j = 0; j < HH; ++j) atomicAdd(ar + j, out[j]);
    }
}

// One thread per node. u_in = [x (64), agg (64)]; x += silu(u_in@w1+b1)@w2+b2
// Weights staged in LDS (fp32, 48 KB). Also refreshes x_h (f16).
__global__ __launch_bounds__(256) void upd_k(
    float* __restrict__ x, unsigned* __restrict__ xh,
    const float* __restrict__ agg,
    const float* __restrict__ w1, const float* __restrict__ b1,
    const float* __restrict__ w2, const float* __restrict__ b2)
{
    __shared__ float w1s[128 * 64];  // 32 KB
    __shared__ float w2s[64 * 64];   // 16 KB
    for (int i = threadIdx.x; i < 128 * 64; i += 256) w1s[i] = w1[i];
    for (int i = threadIdx.x; i < 64 * 64; i += 256) w2s[i] = w2[i];
    __syncthreads();

    int n = blockIdx.x * 256 + threadIdx.x;
    if (n >= NN) return;

    float h[HH];
#pragma unroll
    for (int j = 0; j < HH; ++j) h[j] = b1[j];

    {
        const float4* xi = (const float4*)(x + ((size_t)n << 6));
        for (int i4 = 0; i4 < 16; ++i4) {
            float4 v = xi[i4];
            const float* w = w1s + i4 * 4 * HH;
#pragma unroll
            for (int j = 0; j < HH; ++j) h[j] = fmaf(v.x, w[j], h[j]);
#pragma unroll
            for (int j = 0; j < HH; ++j) h[j] = fmaf(v.y, w[HH + j], h[j]);
#pragma unroll
            for (int j = 0; j < HH; ++j) h[j] = fmaf(v.z, w[2*HH + j], h[j]);
#pragma unroll
            for (int j = 0; j < HH; ++j) h[j] = fmaf(v.w, w[3*HH + j], h[j]);
        }
    }
    {
        const float4* ai = (const float4*)(agg + ((size_t)n << 6));
        for (int i4 = 0; i4 < 16; ++i4) {
            float4 v = ai[i4];
            const float* w = w1s + (64 + i4 * 4) * HH;
#pragma unroll
            for (int j = 0; j < HH; ++j) h[j] = fmaf(v.x, w[j], h[j]);
#pragma unroll
            for (int j = 0; j < HH; ++j) h[j] = fmaf(v.y, w[HH + j], h[j]);
#pragma unroll
            for (int j = 0; j < HH; ++j) h[j] = fmaf(v.z, w[2*HH + j], h[j]);
#pragma unroll
            for (int j = 0; j < HH; ++j) h[j] = fmaf(v.w, w[3*HH + j], h[j]);
        }
    }

#pragma unroll
    for (int k = 0; k < HH; ++k) h[k] = silu_f(h[k]);

    float out[HH];
#pragma unroll
    for (int j = 0; j < HH; ++j) out[j] = b2[j];
#pragma unroll
    for (int k = 0; k < HH; ++k) {
        float hv = h[k];
        const float* w = w2s + k * HH;
#pragma unroll
        for (int j = 0; j < HH; ++j) out[j] = fmaf(hv, w[j], out[j]);
    }

    float* xr = x + ((size_t)n << 6);
    unsigned* xhp = xh + ((size_t)n << 5);
#pragma unroll
    for (int p = 0; p < 32; ++p) {
        float v0 = xr[2*p]   + out[2*p];
        float v1 = xr[2*p+1] + out[2*p+1];
        xr[2*p] = v0; xr[2*p+1] = v1;
        xhp[p] = pk2(v0, v1);
    }
}

// One thread per node: atomic_e = silu(x@w1+b1)@w2 + b2; energy[batch[n]] += e
__global__ __launch_bounds__(256) void head_k(
    const float* __restrict__ x,
    const float* __restrict__ w1, const float* __restrict__ b1,
    const float* __restrict__ w2, const float* __restrict__ b2,
    const int* __restrict__ batch, float* __restrict__ energy)
{
    __shared__ float w1s[64 * 64];  // 16 KB
    for (int i = threadIdx.x; i < 64 * 64; i += 256) w1s[i] = w1[i];
    __syncthreads();

    int n = blockIdx.x * 256 + threadIdx.x;
    if (n >= NN) return;

    float h[HH];
#pragma unroll
    for (int j = 0; j < HH; ++j) h[j] = b1[j];

    const float4* xi = (const float4*)(x + ((size_t)n << 6));
    for (int i4 = 0; i4 < 16; ++i4) {
        float4 v = xi[i4];
        const float* w = w1s + i4 * 4 * HH;
#pragma unroll
        for (int j = 0; j < HH; ++j) h[j] = fmaf(v.x, w[j], h[j]);
#pragma unroll
        for (int j = 0; j < HH; ++j) h[j] = fmaf(v.y, w[HH + j], h[j]);
#pragma unroll
        for (int j = 0; j < HH; ++j) h[j] = fmaf(v.z, w[2*HH + j], h[j]);
#pragma unroll
        for (int j = 0; j < HH; ++j) h[j] = fmaf(v.w, w[3*HH + j], h[j]);
    }

    float e = b2[0];
#pragma unroll
    for (int k = 0; k < HH; ++k) e = fmaf(silu_f(h[k]), w2[k], e);

    atomicAdd(energy + batch[n], e);
}

extern "C" void kernel_launch(void* const* d_in, const int* in_sizes, int n_in,
                              void* d_out, int out_size, void* d_ws, size_t ws_size,
                              hipStream_t stream) {
    const int*   z       = (const int*)  d_in[0];
    const float* pos     = (const float*)d_in[1];
    const int*   eidx    = (const int*)  d_in[2];
    const int*   batch   = (const int*)  d_in[3];
    const float* embed   = (const float*)d_in[4];
    const float* msg_w1  = (const float*)d_in[5];   // (NL, 136, 64)
    const float* msg_b1  = (const float*)d_in[6];   // (NL, 64)
    const float* msg_w2  = (const float*)d_in[7];   // (NL, 64, 64)
    const float* msg_b2  = (const float*)d_in[8];   // (NL, 64)
    const float* upd_w1  = (const float*)d_in[9];   // (NL, 128, 64)
    const float* upd_b1  = (const float*)d_in[10];  // (NL, 64)
    const float* upd_w2  = (const float*)d_in[11];  // (NL, 64, 64)
    const float* upd_b2  = (const float*)d_in[12];  // (NL, 64)
    const float* eh_w1   = (const float*)d_in[13];  // (64, 64)
    const float* eh_b1   = (const float*)d_in[14];  // (64,)
    const float* eh_w2   = (const float*)d_in[15];  // (64, 1)
    const float* eh_b2   = (const float*)d_in[16];  // (1,)

    const int* erow = eidx;
    const int* ecol = eidx + EE;

    // ws layout (4-byte units)
    float*    x      = (float*)d_ws;                      // NN*64
    float*    agg    = x + (size_t)NN * HH;               // NN*64
    unsigned* xh     = (unsigned*)(agg + (size_t)NN * HH);// NN*32
    int*      deg    = (int*)(xh + (size_t)NN * 32);      // NN
    int*      cursor = deg + NN;                          // NN
    int*      bsum   = cursor + NN;                       // 64
    int*      perm   = bsum + 64;                         // EE
    unsigned* wp1    = (unsigned*)(perm + EE);            // NL*68*64
    unsigned* wp2    = wp1 + NLAYER * 68 * 64;            // NL*32*64
    float*    energy = (float*)d_out;

    (void)hipMemsetAsync(energy, 0, NGRAPH * sizeof(float), stream);
    (void)hipMemsetAsync(deg, 0, NN * sizeof(int), stream);

    embed_gather_k<<<(NN * 32 + 255) / 256, 256, 0, stream>>>(z, embed, x, xh);
    pack_w1_k<<<(NLAYER * 68 * 64 + 255) / 256, 256, 0, stream>>>(msg_w1, wp1);
    pack_w2_k<<<(NLAYER * 32 * 64 + 255) / 256, 256, 0, stream>>>(msg_w2, wp2);

    // CSR permutation (edges sorted by col)
    deg_k<<<(EE + 255) / 256, 256, 0, stream>>>(ecol, deg);
    scan1_k<<<NBLK1, 1024, 0, stream>>>(deg, cursor, bsum);
    scan2_k<<<1, 64, 0, stream>>>(bsum);
    scan3_k<<<(NN + 255) / 256, 256, 0, stream>>>(cursor, bsum);
    scatter_k<<<(EE + 255) / 256, 256, 0, stream>>>(ecol, cursor, perm);

    for (int l = 0; l < NLAYER; ++l) {
        (void)hipMemsetAsync(agg, 0, (size_t)NN * HH * sizeof(float), stream);
        msg_k<<<EE / 256, 256, 0, stream>>>(
            pos, erow, ecol, perm, xh,
            wp1 + (size_t)l * 68 * 64,
            msg_b1 + (size_t)l * HH,
            wp2 + (size_t)l * 32 * 64,
            msg_b2 + (size_t)l * HH,
            agg);
        upd_k<<<(NN + 255) / 256, 256, 0, stream>>>(
            x, xh, agg,
            upd_w1 + (size_t)l * 2*HH * HH,
            upd_b1 + (size_t)l * HH,
            upd_w2 + (size_t)l * HH * HH,
            upd_b2 + (size_t)l * HH);
    }

    head_k<<<(NN + 255) / 256, 256, 0, stream>>>(
        x, eh_w1, eh_b1, eh_w2, eh_b2, batch, energy);
}

// Round 6
// 868.933 us; speedup vs baseline: 7.2425x; 1.7947x over previous
//
#include <hip/hip_runtime.h>
#include <math.h>

#define NN 50000
#define EE 800000
#define HH 64
#define NBASIS 8
#define NLAYER 2
#define NGRAPH 64
#define NBLK1 49  // ceil(NN/1024)

// derive the packed-half vector type from the builtin itself so all uses agree
using half2_t = decltype(__builtin_amdgcn_cvt_pkrtz(0.0f, 0.0f));
typedef _Float16 f16x8 __attribute__((ext_vector_type(8)));
typedef float f32x4 __attribute__((ext_vector_type(4)));

union U4H8 { uint4 u; f16x8 h; };

__device__ __forceinline__ float silu_f(float v) {
    return v * (1.0f / (1.0f + __expf(-v)));
}

__device__ __forceinline__ unsigned pk2(float a, float b) {
    union { half2_t h; unsigned u; } x;
    x.h = __builtin_amdgcn_cvt_pkrtz(a, b);
    return x.u;
}

// gather embed -> x (fp32) and x_h (f16 pairs). idx over NN*32 pairs.
__global__ __launch_bounds__(256) void embed_gather_k(
    const int* __restrict__ z, const float* __restrict__ embed,
    float* __restrict__ x, unsigned* __restrict__ xh)
{
    int idx = blockIdx.x * 256 + threadIdx.x;
    if (idx >= NN * 32) return;
    int n = idx >> 5;
    int p = idx & 31;
    const float2* er = (const float2*)(embed + ((size_t)z[n] << 6));
    float2 v = er[p];
    ((float2*)x)[idx] = v;
    xh[idx] = pk2(v.x, v.y);
}

// ---- weight prepack: W1^T [l][feat(64)][k-pairs(80, pad from 68)] f16 ----
__global__ __launch_bounds__(256) void pack_w1t_k(
    const float* __restrict__ msg_w1, unsigned* __restrict__ w1t)
{
    int idx = blockIdx.x * 256 + threadIdx.x;
    if (idx >= NLAYER * 64 * 80) return;
    int l = idx / (64 * 80);
    int rem = idx - l * 64 * 80;
    int f = rem / 80, kp = rem % 80;
    const float* w = msg_w1 + (size_t)l * 136 * 64;
    unsigned v = 0;
    if (kp < 68) v = pk2(w[(2 * kp) * 64 + f], w[(2 * kp + 1) * 64 + f]);
    w1t[idx] = v;
}

// ---- weight prepack: W2^T [l][n(64)][k-pairs(32)] f16 ----
__global__ __launch_bounds__(256) void pack_w2t_k(
    const float* __restrict__ msg_w2, unsigned* __restrict__ w2t)
{
    int idx = blockIdx.x * 256 + threadIdx.x;
    if (idx >= NLAYER * 64 * 32) return;
    int l = idx / (64 * 32);
    int rem = idx - l * 64 * 32;
    int n = rem / 32, kp = rem % 32;
    const float* w = msg_w2 + (size_t)l * 64 * 64;
    w2t[idx] = pk2(w[(2 * kp) * 64 + n], w[(2 * kp + 1) * 64 + n]);
}

// ---- CSR build ----
__global__ __launch_bounds__(256) void deg_k(
    const int* __restrict__ ecol, int* __restrict__ deg)
{
    int e = blockIdx.x * 256 + threadIdx.x;
    if (e < EE) atomicAdd(&deg[ecol[e]], 1);
}

__global__ __launch_bounds__(1024) void scan1_k(
    const int* __restrict__ deg, int* __restrict__ cursor,
    int* __restrict__ bsum)
{
    __shared__ int wsum[16];
    int t = threadIdx.x, lane = t & 63, wave = t >> 6;
    int i = blockIdx.x * 1024 + t;
    int v = (i < NN) ? deg[i] : 0;
    int s = v;
#pragma unroll
    for (int off = 1; off < 64; off <<= 1) {
        int tv = __shfl_up(s, off, 64);
        if (lane >= off) s += tv;
    }
    if (lane == 63) wsum[wave] = s;
    __syncthreads();
    if (wave == 0) {
        int ws = (lane < 16) ? wsum[lane] : 0;
        int ss = ws;
#pragma unroll
        for (int off = 1; off < 16; off <<= 1) {
            int tv = __shfl_up(ss, off, 64);
            if (lane >= off) ss += tv;
        }
        if (lane < 16) wsum[lane] = ss - ws;
    }
    __syncthreads();
    int excl = wsum[wave] + s - v;
    if (i < NN) cursor[i] = excl;
    if (t == 1023) bsum[blockIdx.x] = excl + v;
}

__global__ __launch_bounds__(64) void scan2_k(int* __restrict__ bsum)
{
    int lane = threadIdx.x;
    int v = (lane < NBLK1) ? bsum[lane] : 0;
    int s = v;
#pragma unroll
    for (int off = 1; off < 64; off <<= 1) {
        int tv = __shfl_up(s, off, 64);
        if (lane >= off) s += tv;
    }
    if (lane < NBLK1) bsum[lane] = s - v;
}

__global__ __launch_bounds__(256) void scan3_k(
    int* __restrict__ cursor, const int* __restrict__ bsum)
{
    int i = blockIdx.x * 256 + threadIdx.x;
    if (i < NN) cursor[i] += bsum[i >> 10];
}

__global__ __launch_bounds__(256) void scatter_k(
    const int* __restrict__ ecol, int* __restrict__ cursor,
    int* __restrict__ perm)
{
    int e = blockIdx.x * 256 + threadIdx.x;
    if (e < EE) {
        int slot = atomicAdd(&cursor[ecol[e]], 1);
        perm[slot] = e;
    }
}

// MFMA msg kernel: one wave (block=64) per 64 sorted edge slots.
// GEMM1 transposed: H^T(feat,edge) = W1T(A) @ msg_in^T(B), K=160 (pad 136).
// GEMM2: M(edge,out) = P(A, via shuffles) @ W2(B, from W2T), K=64.
// Reduce: per-column serial segmented scan over 32-edge strips in LDS.
__global__ __launch_bounds__(64) void msg_k(
    const float* __restrict__ pos,
    const int* __restrict__ erow, const int* __restrict__ ecol,
    const int* __restrict__ perm,
    const unsigned* __restrict__ xh,
    const unsigned* __restrict__ w1t, const float* __restrict__ b1,
    const unsigned* __restrict__ w2t, const float* __restrict__ b2,
    float* __restrict__ agg)
{
    __shared__ __align__(16) unsigned earr[64 * 4];  // 64 edges x 8 f16
    __shared__ int ckey_s[64];
    __shared__ int rkey_s[64];
    __shared__ float Mbuf[64 * 33];                  // [edge][col+pad]

    const int lane = threadIdx.x;
    const int q = lane >> 4, n15 = lane & 15;
    const int slot = blockIdx.x * 64 + lane;         // EE % 64 == 0

    // ---- per-edge prep ----
    {
        int e = perm[slot];
        int r = erow[e], c = ecol[e];
        ckey_s[lane] = c;
        rkey_s[lane] = r;
        float dx = pos[3*r]   - pos[3*c];
        float dy = pos[3*r+1] - pos[3*c+1];
        float dz = pos[3*r+2] - pos[3*c+2];
        float d = sqrtf(dx*dx + dy*dy + dz*dz);
        float env = 0.0f;
        if (d < 5.0f) {
            float cv = __cosf(d * 0.31415926535897932f);  // pi/(2*CUTOFF)
            env = cv * cv;
        }
        float scale = (d > 0.0f) ? (env / d) : env;
        float ea[NBASIS];
#pragma unroll
        for (int k = 0; k < NBASIS; ++k)
            ea[k] = __sinf((float)(k + 1) * 0.62831853071795865f * d) * scale;
#pragma unroll
        for (int p = 0; p < 4; ++p)
            earr[lane * 4 + p] = pk2(ea[2*p], ea[2*p+1]);
    }
    __syncthreads();

    // ---- B-frags for GEMM1: msg_in^T[k][edge], edge = nt*16 + n15 ----
    // k-chunk = 32*ks + 8*q: ks 0,1 from xh[c], 2,3 from xh[r], 4 = ea/zero
    U4H8 bf[5][4];
#pragma unroll
    for (int nt = 0; nt < 4; ++nt) {
        int eB = nt * 16 + n15;
        int cn = ckey_s[eB], rn = rkey_s[eB];
        const uint4* cp = (const uint4*)(xh + ((size_t)cn << 5));
        const uint4* rp = (const uint4*)(xh + ((size_t)rn << 5));
        bf[0][nt].u = cp[q];
        bf[1][nt].u = cp[4 + q];
        bf[2][nt].u = rp[q];
        bf[3][nt].u = rp[4 + q];
        uint4 zz; zz.x = zz.y = zz.z = zz.w = 0;
        bf[4][nt].u = (q == 0) ? *(const uint4*)(earr + eB * 4) : zz;
    }

    // ---- GEMM1: acc1[mt][nt], C-layout: row=feat=16mt+4q+reg, col=edge=16nt+n15
    f32x4 acc1[4][4];
#pragma unroll
    for (int mt = 0; mt < 4; ++mt) {
        f32x4 binit = *(const f32x4*)(b1 + mt * 16 + q * 4);
#pragma unroll
        for (int nt = 0; nt < 4; ++nt) acc1[mt][nt] = binit;
    }
#pragma unroll
    for (int ks = 0; ks < 5; ++ks) {
#pragma unroll
        for (int mt = 0; mt < 4; ++mt) {
            U4H8 af;
            af.u = *(const uint4*)(w1t + (size_t)(mt * 16 + n15) * 80 + ks * 16 + q * 4);
#pragma unroll
            for (int nt = 0; nt < 4; ++nt)
                acc1[mt][nt] = __builtin_amdgcn_mfma_f32_16x16x32_f16(
                    af.h, bf[ks][nt].h, acc1[mt][nt], 0, 0, 0);
        }
    }

    // ---- silu + pack pairs: psrc[mt][nt][p] = f16 pair (feat 4q+2p, +1) ----
    unsigned psrc[4][4][2];
#pragma unroll
    for (int mt = 0; mt < 4; ++mt)
#pragma unroll
        for (int nt = 0; nt < 4; ++nt) {
            psrc[mt][nt][0] = pk2(silu_f(acc1[mt][nt][0]), silu_f(acc1[mt][nt][1]));
            psrc[mt][nt][1] = pk2(silu_f(acc1[mt][nt][2]), silu_f(acc1[mt][nt][3]));
        }

    // ---- GEMM2: acc2[et][nt], C-layout: row=edge=16et+4q+reg, col=out=16nt+n15
    f32x4 acc2[4][4];
#pragma unroll
    for (int nt = 0; nt < 4; ++nt) {
        float b2v = b2[nt * 16 + n15];
        f32x4 binit; binit[0] = b2v; binit[1] = b2v; binit[2] = b2v; binit[3] = b2v;
#pragma unroll
        for (int et = 0; et < 4; ++et) acc2[et][nt] = binit;
    }
#pragma unroll
    for (int ks2 = 0; ks2 < 2; ++ks2) {
        U4H8 wb[4];
#pragma unroll
        for (int nt = 0; nt < 4; ++nt)
            wb[nt].u = *(const uint4*)(w2t + (size_t)(nt * 16 + n15) * 32 + ks2 * 16 + q * 4);
#pragma unroll
        for (int et = 0; et < 4; ++et) {
            // A-frag: P[edge=16et+n15][k=32ks2+8q+j] via shuffles from acc1/psrc
            unsigned tmp[4];
#pragma unroll
            for (int jr = 0; jr < 4; ++jr) {
                int srcl = (2 * (q & 1) + (jr >> 1)) * 16 + n15;
                unsigned v0 = (unsigned)__shfl((int)psrc[2 * ks2][et][jr & 1], srcl, 64);
                unsigned v1 = (unsigned)__shfl((int)psrc[2 * ks2 + 1][et][jr & 1], srcl, 64);
                tmp[jr] = (q >> 1) ? v1 : v0;
            }
            U4H8 pf;
            pf.u.x = tmp[0]; pf.u.y = tmp[1]; pf.u.z = tmp[2]; pf.u.w = tmp[3];
#pragma unroll
            for (int nt = 0; nt < 4; ++nt)
                acc2[et][nt] = __builtin_amdgcn_mfma_f32_16x16x32_f16(
                    pf.h, wb[nt].h, acc2[et][nt], 0, 0, 0);
        }
    }

    // ---- segmented reduce over edges, two column-halves through LDS ----
#pragma unroll
    for (int hf = 0; hf < 2; ++hf) {
#pragma unroll
        for (int et = 0; et < 4; ++et)
#pragma unroll
            for (int t2 = 0; t2 < 2; ++t2) {
                int nt = 2 * hf + t2;
                int cl = t2 * 16 + n15;
                int eb = et * 16 + q * 4;
#pragma unroll
                for (int r = 0; r < 4; ++r)
                    Mbuf[(eb + r) * 33 + cl] = acc2[et][nt][r];
            }
        __syncthreads();
        {
            int cl = lane & 31, st = lane >> 5;
            int ebase = 32 * st;
            float run = 0.0f;
            int runkey = ckey_s[ebase];
            bool atstart = true;
#pragma unroll
            for (int i = 0; i < 32; ++i) {
                int kk = ckey_s[ebase + i];
                float v = Mbuf[(ebase + i) * 33 + cl];
                if (kk != runkey) {
                    float* dst = agg + ((size_t)runkey << 6) + hf * 32 + cl;
                    if (atstart) atomicAdd(dst, run); else *dst = run;
                    run = 0.0f; runkey = kk; atstart = false;
                }
                run += v;
            }
            atomicAdd(agg + ((size_t)runkey << 6) + hf * 32 + cl, run);
        }
        __syncthreads();
    }
}

// One thread per node. u_in = [x (64), agg (64)]; x += silu(u_in@w1+b1)@w2+b2
// Weights staged in LDS (fp32, 48 KB). Also refreshes x_h (f16).
__global__ __launch_bounds__(256) void upd_k(
    float* __restrict__ x, unsigned* __restrict__ xh,
    const float* __restrict__ agg,
    const float* __restrict__ w1, const float* __restrict__ b1,
    const float* __restrict__ w2, const float* __restrict__ b2)
{
    __shared__ float w1s[128 * 64];  // 32 KB
    __shared__ float w2s[64 * 64];   // 16 KB
    for (int i = threadIdx.x; i < 128 * 64; i += 256) w1s[i] = w1[i];
    for (int i = threadIdx.x; i < 64 * 64; i += 256) w2s[i] = w2[i];
    __syncthreads();

    int n = blockIdx.x * 256 + threadIdx.x;
    if (n >= NN) return;

    float h[HH];
#pragma unroll
    for (int j = 0; j < HH; ++j) h[j] = b1[j];

    {
        const float4* xi = (const float4*)(x + ((size_t)n << 6));
        for (int i4 = 0; i4 < 16; ++i4) {
            float4 v = xi[i4];
            const float* w = w1s + i4 * 4 * HH;
#pragma unroll
            for (int j = 0; j < HH; ++j) h[j] = fmaf(v.x, w[j], h[j]);
#pragma unroll
            for (int j = 0; j < HH; ++j) h[j] = fmaf(v.y, w[HH + j], h[j]);
#pragma unroll
            for (int j = 0; j < HH; ++j) h[j] = fmaf(v.z, w[2*HH + j], h[j]);
#pragma unroll
            for (int j = 0; j < HH; ++j) h[j] = fmaf(v.w, w[3*HH + j], h[j]);
        }
    }
    {
        const float4* ai = (const float4*)(agg + ((size_t)n << 6));
        for (int i4 = 0; i4 < 16; ++i4) {
            float4 v = ai[i4];
            const float* w = w1s + (64 + i4 * 4) * HH;
#pragma unroll
            for (int j = 0; j < HH; ++j) h[j] = fmaf(v.x, w[j], h[j]);
#pragma unroll
            for (int j = 0; j < HH; ++j) h[j] = fmaf(v.y, w[HH + j], h[j]);
#pragma unroll
            for (int j = 0; j < HH; ++j) h[j] = fmaf(v.z, w[2*HH + j], h[j]);
#pragma unroll
            for (int j = 0; j < HH; ++j) h[j] = fmaf(v.w, w[3*HH + j], h[j]);
        }
    }

#pragma unroll
    for (int k = 0; k < HH; ++k) h[k] = silu_f(h[k]);

    float out[HH];
#pragma unroll
    for (int j = 0; j < HH; ++j) out[j] = b2[j];
#pragma unroll
    for (int k = 0; k < HH; ++k) {
        float hv = h[k];
        const float* w = w2s + k * HH;
#pragma unroll
        for (int j = 0; j < HH; ++j) out[j] = fmaf(hv, w[j], out[j]);
    }

    float* xr = x + ((size_t)n << 6);
    unsigned* xhp = xh + ((size_t)n << 5);
#pragma unroll
    for (int p = 0; p < 32; ++p) {
        float v0 = xr[2*p]   + out[2*p];
        float v1 = xr[2*p+1] + out[2*p+1];
        xr[2*p] = v0; xr[2*p+1] = v1;
        xhp[p] = pk2(v0, v1);
    }
}

// One thread per node: atomic_e = silu(x@w1+b1)@w2 + b2; energy[batch[n]] += e
__global__ __launch_bounds__(256) void head_k(
    const float* __restrict__ x,
    const float* __restrict__ w1, const float* __restrict__ b1,
    const float* __restrict__ w2, const float* __restrict__ b2,
    const int* __restrict__ batch, float* __restrict__ energy)
{
    __shared__ float w1s[64 * 64];  // 16 KB
    for (int i = threadIdx.x; i < 64 * 64; i += 256) w1s[i] = w1[i];
    __syncthreads();

    int n = blockIdx.x * 256 + threadIdx.x;
    if (n >= NN) return;

    float h[HH];
#pragma unroll
    for (int j = 0; j < HH; ++j) h[j] = b1[j];

    const float4* xi = (const float4*)(x + ((size_t)n << 6));
    for (int i4 = 0; i4 < 16; ++i4) {
        float4 v = xi[i4];
        const float* w = w1s + i4 * 4 * HH;
#pragma unroll
        for (int j = 0; j < HH; ++j) h[j] = fmaf(v.x, w[j], h[j]);
#pragma unroll
        for (int j = 0; j < HH; ++j) h[j] = fmaf(v.y, w[HH + j], h[j]);
#pragma unroll
        for (int j = 0; j < HH; ++j) h[j] = fmaf(v.z, w[2*HH + j], h[j]);
#pragma unroll
        for (int j = 0; j < HH; ++j) h[j] = fmaf(v.w, w[3*HH + j], h[j]);
    }

    float e = b2[0];
#pragma unroll
    for (int k = 0; k < HH; ++k) e = fmaf(silu_f(h[k]), w2[k], e);

    atomicAdd(energy + batch[n], e);
}

extern "C" void kernel_launch(void* const* d_in, const int* in_sizes, int n_in,
                              void* d_out, int out_size, void* d_ws, size_t ws_size,
                              hipStream_t stream) {
    const int*   z       = (const int*)  d_in[0];
    const float* pos     = (const float*)d_in[1];
    const int*   eidx    = (const int*)  d_in[2];
    const int*   batch   = (const int*)  d_in[3];
    const float* embed   = (const float*)d_in[4];
    const float* msg_w1  = (const float*)d_in[5];   // (NL, 136, 64)
    const float* msg_b1  = (const float*)d_in[6];   // (NL, 64)
    const float* msg_w2  = (const float*)d_in[7];   // (NL, 64, 64)
    const float* msg_b2  = (const float*)d_in[8];   // (NL, 64)
    const float* upd_w1  = (const float*)d_in[9];   // (NL, 128, 64)
    const float* upd_b1  = (const float*)d_in[10];  // (NL, 64)
    const float* upd_w2  = (const float*)d_in[11];  // (NL, 64, 64)
    const float* upd_b2  = (const float*)d_in[12];  // (NL, 64)
    const float* eh_w1   = (const float*)d_in[13];  // (64, 64)
    const float* eh_b1   = (const float*)d_in[14];  // (64,)
    const float* eh_w2   = (const float*)d_in[15];  // (64, 1)
    const float* eh_b2   = (const float*)d_in[16];  // (1,)

    const int* erow = eidx;
    const int* ecol = eidx + EE;

    // ws layout (4-byte units)
    float*    x      = (float*)d_ws;                      // NN*64
    float*    agg    = x + (size_t)NN * HH;               // NN*64
    unsigned* xh     = (unsigned*)(agg + (size_t)NN * HH);// NN*32
    int*      deg    = (int*)(xh + (size_t)NN * 32);      // NN
    int*      cursor = deg + NN;                          // NN
    int*      bsum   = cursor + NN;                       // 64
    int*      perm   = bsum + 64;                         // EE
    unsigned* w1t    = (unsigned*)(perm + EE);            // NL*64*80
    unsigned* w2t    = w1t + NLAYER * 64 * 80;            // NL*64*32
    float*    energy = (float*)d_out;

    (void)hipMemsetAsync(energy, 0, NGRAPH * sizeof(float), stream);
    (void)hipMemsetAsync(deg, 0, NN * sizeof(int), stream);

    embed_gather_k<<<(NN * 32 + 255) / 256, 256, 0, stream>>>(z, embed, x, xh);
    pack_w1t_k<<<(NLAYER * 64 * 80 + 255) / 256, 256, 0, stream>>>(msg_w1, w1t);
    pack_w2t_k<<<(NLAYER * 64 * 32 + 255) / 256, 256, 0, stream>>>(msg_w2, w2t);

    // CSR permutation (edges sorted by col)
    deg_k<<<(EE + 255) / 256, 256, 0, stream>>>(ecol, deg);
    scan1_k<<<NBLK1, 1024, 0, stream>>>(deg, cursor, bsum);
    scan2_k<<<1, 64, 0, stream>>>(bsum);
    scan3_k<<<(NN + 255) / 256, 256, 0, stream>>>(cursor, bsum);
    scatter_k<<<(EE + 255) / 256, 256, 0, stream>>>(ecol, cursor, perm);

    for (int l = 0; l < NLAYER; ++l) {
        (void)hipMemsetAsync(agg, 0, (size_t)NN * HH * sizeof(float), stream);
        msg_k<<<EE / 64, 64, 0, stream>>>(
            pos, erow, ecol, perm, xh,
            w1t + (size_t)l * 64 * 80,
            msg_b1 + (size_t)l * HH,
            w2t + (size_t)l * 64 * 32,
            msg_b2 + (size_t)l * HH,
            agg);
        upd_k<<<(NN + 255) / 256, 256, 0, stream>>>(
            x, xh, agg,
            upd_w1 + (size_t)l * 2*HH * HH,
            upd_b1 + (size_t)l * HH,
            upd_w2 + (size_t)l * HH * HH,
            upd_b2 + (size_t)l * HH);
    }

    head_k<<<(NN + 255) / 256, 256, 0, stream>>>(
        x, eh_w1, eh_b1, eh_w2, eh_b2, batch, energy);
}

// Round 7
// 473.840 us; speedup vs baseline: 13.2813x; 1.8338x over previous
//
#include <hip/hip_runtime.h>
#include <math.h>

#define NN 50000
#define EE 800000
#define HH 64
#define NBASIS 8
#define NLAYER 2
#define NGRAPH 64
#define NBLK1 49  // ceil(NN/1024)

// derive the packed-half vector type from the builtin itself so all uses agree
using half2_t = decltype(__builtin_amdgcn_cvt_pkrtz(0.0f, 0.0f));
typedef _Float16 f16x8 __attribute__((ext_vector_type(8)));
typedef float f32x4 __attribute__((ext_vector_type(4)));

union U4H8 { uint4 u; f16x8 h; };

__device__ __forceinline__ float silu_f(float v) {
    return v * (1.0f / (1.0f + __expf(-v)));
}

__device__ __forceinline__ unsigned pk2(float a, float b) {
    union { half2_t h; unsigned u; } x;
    x.h = __builtin_amdgcn_cvt_pkrtz(a, b);
    return x.u;
}

// gather embed -> x (fp32) and x_h (f16 pairs). idx over NN*32 pairs.
__global__ __launch_bounds__(256) void embed_gather_k(
    const int* __restrict__ z, const float* __restrict__ embed,
    float* __restrict__ x, unsigned* __restrict__ xh)
{
    int idx = blockIdx.x * 256 + threadIdx.x;
    if (idx >= NN * 32) return;
    int n = idx >> 5;
    int p = idx & 31;
    const float2* er = (const float2*)(embed + ((size_t)z[n] << 6));
    float2 v = er[p];
    ((float2*)x)[idx] = v;
    xh[idx] = pk2(v.x, v.y);
}

// ---- msg weight prepack: W1^T [l][feat(64)][k-pairs(80, pad from 68)] ----
__global__ __launch_bounds__(256) void pack_w1t_k(
    const float* __restrict__ msg_w1, unsigned* __restrict__ w1t)
{
    int idx = blockIdx.x * 256 + threadIdx.x;
    if (idx >= NLAYER * 64 * 80) return;
    int l = idx / (64 * 80);
    int rem = idx - l * 64 * 80;
    int f = rem / 80, kp = rem % 80;
    const float* w = msg_w1 + (size_t)l * 136 * 64;
    unsigned v = 0;
    if (kp < 68) v = pk2(w[(2 * kp) * 64 + f], w[(2 * kp + 1) * 64 + f]);
    w1t[idx] = v;
}

// ---- msg weight prepack: W2^T [l][n(64)][k-pairs(32)] ----
__global__ __launch_bounds__(256) void pack_w2t_k(
    const float* __restrict__ msg_w2, unsigned* __restrict__ w2t)
{
    int idx = blockIdx.x * 256 + threadIdx.x;
    if (idx >= NLAYER * 64 * 32) return;
    int l = idx / (64 * 32);
    int rem = idx - l * 64 * 32;
    int n = rem / 32, kp = rem % 32;
    const float* w = msg_w2 + (size_t)l * 64 * 64;
    w2t[idx] = pk2(w[(2 * kp) * 64 + n], w[(2 * kp + 1) * 64 + n]);
}

// ---- upd weight prepack: W1^T [l][feat(64)][k-pairs(64)] ----
__global__ __launch_bounds__(256) void pack_uw1t_k(
    const float* __restrict__ upd_w1, unsigned* __restrict__ w1tu)
{
    int idx = blockIdx.x * 256 + threadIdx.x;
    if (idx >= NLAYER * 64 * 64) return;
    int l = idx / (64 * 64);
    int rem = idx - l * 64 * 64;
    int f = rem >> 6, kp = rem & 63;
    const float* w = upd_w1 + (size_t)l * 128 * 64;
    w1tu[idx] = pk2(w[(2 * kp) * 64 + f], w[(2 * kp + 1) * 64 + f]);
}

// ---- upd weight prepack: W2^T [l][n(64)][k-pairs(32)] ----
__global__ __launch_bounds__(256) void pack_uw2t_k(
    const float* __restrict__ upd_w2, unsigned* __restrict__ w2tu)
{
    int idx = blockIdx.x * 256 + threadIdx.x;
    if (idx >= NLAYER * 64 * 32) return;
    int l = idx / (64 * 32);
    int rem = idx - l * 64 * 32;
    int n = rem / 32, kp = rem % 32;
    const float* w = upd_w2 + (size_t)l * 64 * 64;
    w2tu[idx] = pk2(w[(2 * kp) * 64 + n], w[(2 * kp + 1) * 64 + n]);
}

// ---- CSR build ----
__global__ __launch_bounds__(256) void deg_k(
    const int* __restrict__ ecol, int* __restrict__ deg)
{
    int e = blockIdx.x * 256 + threadIdx.x;
    if (e < EE) atomicAdd(&deg[ecol[e]], 1);
}

__global__ __launch_bounds__(1024) void scan1_k(
    const int* __restrict__ deg, int* __restrict__ cursor,
    int* __restrict__ bsum)
{
    __shared__ int wsum[16];
    int t = threadIdx.x, lane = t & 63, wave = t >> 6;
    int i = blockIdx.x * 1024 + t;
    int v = (i < NN) ? deg[i] : 0;
    int s = v;
#pragma unroll
    for (int off = 1; off < 64; off <<= 1) {
        int tv = __shfl_up(s, off, 64);
        if (lane >= off) s += tv;
    }
    if (lane == 63) wsum[wave] = s;
    __syncthreads();
    if (wave == 0) {
        int ws = (lane < 16) ? wsum[lane] : 0;
        int ss = ws;
#pragma unroll
        for (int off = 1; off < 16; off <<= 1) {
            int tv = __shfl_up(ss, off, 64);
            if (lane >= off) ss += tv;
        }
        if (lane < 16) wsum[lane] = ss - ws;
    }
    __syncthreads();
    int excl = wsum[wave] + s - v;
    if (i < NN) cursor[i] = excl;
    if (t == 1023) bsum[blockIdx.x] = excl + v;
}

__global__ __launch_bounds__(64) void scan2_k(int* __restrict__ bsum)
{
    int lane = threadIdx.x;
    int v = (lane < NBLK1) ? bsum[lane] : 0;
    int s = v;
#pragma unroll
    for (int off = 1; off < 64; off <<= 1) {
        int tv = __shfl_up(s, off, 64);
        if (lane >= off) s += tv;
    }
    if (lane < NBLK1) bsum[lane] = s - v;
}

__global__ __launch_bounds__(256) void scan3_k(
    int* __restrict__ cursor, const int* __restrict__ bsum)
{
    int i = blockIdx.x * 256 + threadIdx.x;
    if (i < NN) cursor[i] += bsum[i >> 10];
}

__global__ __launch_bounds__(256) void scatter_k(
    const int* __restrict__ ecol, int* __restrict__ cursor,
    int* __restrict__ perm)
{
    int e = blockIdx.x * 256 + threadIdx.x;
    if (e < EE) {
        int slot = atomicAdd(&cursor[ecol[e]], 1);
        perm[slot] = e;
    }
}

// MFMA msg kernel: one wave (block=64) per 64 sorted edge slots.
__global__ __launch_bounds__(64) void msg_k(
    const float* __restrict__ pos,
    const int* __restrict__ erow, const int* __restrict__ ecol,
    const int* __restrict__ perm,
    const unsigned* __restrict__ xh,
    const unsigned* __restrict__ w1t, const float* __restrict__ b1,
    const unsigned* __restrict__ w2t, const float* __restrict__ b2,
    float* __restrict__ agg)
{
    __shared__ __align__(16) unsigned earr[64 * 4];  // 64 edges x 8 f16
    __shared__ int ckey_s[64];
    __shared__ int rkey_s[64];
    __shared__ float Mbuf[64 * 33];                  // [edge][col+pad]

    const int lane = threadIdx.x;
    const int q = lane >> 4, n15 = lane & 15;
    const int slot = blockIdx.x * 64 + lane;         // EE % 64 == 0

    // ---- per-edge prep ----
    {
        int e = perm[slot];
        int r = erow[e], c = ecol[e];
        ckey_s[lane] = c;
        rkey_s[lane] = r;
        float dx = pos[3*r]   - pos[3*c];
        float dy = pos[3*r+1] - pos[3*c+1];
        float dz = pos[3*r+2] - pos[3*c+2];
        float d = sqrtf(dx*dx + dy*dy + dz*dz);
        float env = 0.0f;
        if (d < 5.0f) {
            float cv = __cosf(d * 0.31415926535897932f);  // pi/(2*CUTOFF)
            env = cv * cv;
        }
        float scale = (d > 0.0f) ? (env / d) : env;
        float ea[NBASIS];
#pragma unroll
        for (int k = 0; k < NBASIS; ++k)
            ea[k] = __sinf((float)(k + 1) * 0.62831853071795865f * d) * scale;
#pragma unroll
        for (int p = 0; p < 4; ++p)
            earr[lane * 4 + p] = pk2(ea[2*p], ea[2*p+1]);
    }
    __syncthreads();

    // ---- B-frags for GEMM1: msg_in^T[k][edge], edge = nt*16 + n15 ----
    U4H8 bf[5][4];
#pragma unroll
    for (int nt = 0; nt < 4; ++nt) {
        int eB = nt * 16 + n15;
        int cn = ckey_s[eB], rn = rkey_s[eB];
        const uint4* cp = (const uint4*)(xh + ((size_t)cn << 5));
        const uint4* rp = (const uint4*)(xh + ((size_t)rn << 5));
        bf[0][nt].u = cp[q];
        bf[1][nt].u = cp[4 + q];
        bf[2][nt].u = rp[q];
        bf[3][nt].u = rp[4 + q];
        uint4 zz; zz.x = zz.y = zz.z = zz.w = 0;
        bf[4][nt].u = (q == 0) ? *(const uint4*)(earr + eB * 4) : zz;
    }

    // ---- GEMM1: C-layout: row=feat=16mt+4q+reg, col=edge=16nt+n15 ----
    f32x4 acc1[4][4];
#pragma unroll
    for (int mt = 0; mt < 4; ++mt) {
        f32x4 binit = *(const f32x4*)(b1 + mt * 16 + q * 4);
#pragma unroll
        for (int nt = 0; nt < 4; ++nt) acc1[mt][nt] = binit;
    }
#pragma unroll
    for (int ks = 0; ks < 5; ++ks) {
#pragma unroll
        for (int mt = 0; mt < 4; ++mt) {
            U4H8 af;
            af.u = *(const uint4*)(w1t + (size_t)(mt * 16 + n15) * 80 + ks * 16 + q * 4);
#pragma unroll
            for (int nt = 0; nt < 4; ++nt)
                acc1[mt][nt] = __builtin_amdgcn_mfma_f32_16x16x32_f16(
                    af.h, bf[ks][nt].h, acc1[mt][nt], 0, 0, 0);
        }
    }

    // ---- silu + pack pairs ----
    unsigned psrc[4][4][2];
#pragma unroll
    for (int mt = 0; mt < 4; ++mt)
#pragma unroll
        for (int nt = 0; nt < 4; ++nt) {
            psrc[mt][nt][0] = pk2(silu_f(acc1[mt][nt][0]), silu_f(acc1[mt][nt][1]));
            psrc[mt][nt][1] = pk2(silu_f(acc1[mt][nt][2]), silu_f(acc1[mt][nt][3]));
        }

    // ---- GEMM2: C-layout: row=edge=16et+4q+reg, col=out=16nt+n15 ----
    f32x4 acc2[4][4];
#pragma unroll
    for (int nt = 0; nt < 4; ++nt) {
        float b2v = b2[nt * 16 + n15];
        f32x4 binit; binit[0] = b2v; binit[1] = b2v; binit[2] = b2v; binit[3] = b2v;
#pragma unroll
        for (int et = 0; et < 4; ++et) acc2[et][nt] = binit;
    }
#pragma unroll
    for (int ks2 = 0; ks2 < 2; ++ks2) {
        U4H8 wb[4];
#pragma unroll
        for (int nt = 0; nt < 4; ++nt)
            wb[nt].u = *(const uint4*)(w2t + (size_t)(nt * 16 + n15) * 32 + ks2 * 16 + q * 4);
#pragma unroll
        for (int et = 0; et < 4; ++et) {
            unsigned tmp[4];
#pragma unroll
            for (int jr = 0; jr < 4; ++jr) {
                int srcl = (2 * (q & 1) + (jr >> 1)) * 16 + n15;
                unsigned v0 = (unsigned)__shfl((int)psrc[2 * ks2][et][jr & 1], srcl, 64);
                unsigned v1 = (unsigned)__shfl((int)psrc[2 * ks2 + 1][et][jr & 1], srcl, 64);
                tmp[jr] = (q >> 1) ? v1 : v0;
            }
            U4H8 pf;
            pf.u.x = tmp[0]; pf.u.y = tmp[1]; pf.u.z = tmp[2]; pf.u.w = tmp[3];
#pragma unroll
            for (int nt = 0; nt < 4; ++nt)
                acc2[et][nt] = __builtin_amdgcn_mfma_f32_16x16x32_f16(
                    pf.h, wb[nt].h, acc2[et][nt], 0, 0, 0);
        }
    }

    // ---- segmented reduce over edges, two column-halves through LDS ----
#pragma unroll
    for (int hf = 0; hf < 2; ++hf) {
#pragma unroll
        for (int et = 0; et < 4; ++et)
#pragma unroll
            for (int t2 = 0; t2 < 2; ++t2) {
                int nt = 2 * hf + t2;
                int cl = t2 * 16 + n15;
                int eb = et * 16 + q * 4;
#pragma unroll
                for (int r = 0; r < 4; ++r)
                    Mbuf[(eb + r) * 33 + cl] = acc2[et][nt][r];
            }
        __syncthreads();
        {
            int cl = lane & 31, st = lane >> 5;
            int ebase = 32 * st;
            float run = 0.0f;
            int runkey = ckey_s[ebase];
            bool atstart = true;
#pragma unroll
            for (int i = 0; i < 32; ++i) {
                int kk = ckey_s[ebase + i];
                float v = Mbuf[(ebase + i) * 33 + cl];
                if (kk != runkey) {
                    float* dst = agg + ((size_t)runkey << 6) + hf * 32 + cl;
                    if (atstart) atomicAdd(dst, run); else *dst = run;
                    run = 0.0f; runkey = kk; atstart = false;
                }
                run += v;
            }
            atomicAdd(agg + ((size_t)runkey << 6) + hf * 32 + cl, run);
        }
        __syncthreads();
    }
}

// MFMA upd kernel: one wave per 64 nodes.
// u_in = [x (64, from xh f16), agg (64, packed on the fly)]
// x += silu(u_in@W1+b1)@W2+b2; refresh xh.
__global__ __launch_bounds__(64) void upd_k(
    float* __restrict__ x, unsigned* __restrict__ xh,
    const float* __restrict__ agg,
    const unsigned* __restrict__ w1t, const float* __restrict__ b1,
    const unsigned* __restrict__ w2t, const float* __restrict__ b2)
{
    __shared__ float Mbuf[64 * 33];

    const int lane = threadIdx.x;
    const int q = lane >> 4, n15 = lane & 15;
    const int nbase = blockIdx.x * 64;

    // ---- B-frags: ks 0,1 from xh; ks 2,3 from agg (pack on the fly) ----
    U4H8 bf[4][4];
#pragma unroll
    for (int nt = 0; nt < 4; ++nt) {
        int node = nbase + nt * 16 + n15;
        int nc = (node < NN) ? node : (NN - 1);
        const uint4* xp = (const uint4*)(xh + ((size_t)nc << 5));
        bf[0][nt].u = xp[q];
        bf[1][nt].u = xp[4 + q];
        const float4* ap = (const float4*)(agg + ((size_t)nc << 6));
        float4 a0 = ap[2*q], a1 = ap[2*q + 1];         // agg k 8q..8q+7
        float4 a2 = ap[8 + 2*q], a3 = ap[8 + 2*q + 1]; // agg k 32+8q..
        bf[2][nt].u.x = pk2(a0.x, a0.y); bf[2][nt].u.y = pk2(a0.z, a0.w);
        bf[2][nt].u.z = pk2(a1.x, a1.y); bf[2][nt].u.w = pk2(a1.z, a1.w);
        bf[3][nt].u.x = pk2(a2.x, a2.y); bf[3][nt].u.y = pk2(a2.z, a2.w);
        bf[3][nt].u.z = pk2(a3.x, a3.y); bf[3][nt].u.w = pk2(a3.z, a3.w);
    }

    // ---- GEMM1: H^T = W1T @ u_in^T, K=128 ----
    f32x4 acc1[4][4];
#pragma unroll
    for (int mt = 0; mt < 4; ++mt) {
        f32x4 binit = *(const f32x4*)(b1 + mt * 16 + q * 4);
#pragma unroll
        for (int nt = 0; nt < 4; ++nt) acc1[mt][nt] = binit;
    }
#pragma unroll
    for (int ks = 0; ks < 4; ++ks) {
#pragma unroll
        for (int mt = 0; mt < 4; ++mt) {
            U4H8 af;
            af.u = *(const uint4*)(w1t + (size_t)(mt * 16 + n15) * 64 + ks * 16 + q * 4);
#pragma unroll
            for (int nt = 0; nt < 4; ++nt)
                acc1[mt][nt] = __builtin_amdgcn_mfma_f32_16x16x32_f16(
                    af.h, bf[ks][nt].h, acc1[mt][nt], 0, 0, 0);
        }
    }

    // ---- silu + pack ----
    unsigned psrc[4][4][2];
#pragma unroll
    for (int mt = 0; mt < 4; ++mt)
#pragma unroll
        for (int nt = 0; nt < 4; ++nt) {
            psrc[mt][nt][0] = pk2(silu_f(acc1[mt][nt][0]), silu_f(acc1[mt][nt][1]));
            psrc[mt][nt][1] = pk2(silu_f(acc1[mt][nt][2]), silu_f(acc1[mt][nt][3]));
        }

    // ---- GEMM2: out = P @ W2, K=64 ----
    f32x4 acc2[4][4];
#pragma unroll
    for (int nt = 0; nt < 4; ++nt) {
        float b2v = b2[nt * 16 + n15];
        f32x4 binit; binit[0] = b2v; binit[1] = b2v; binit[2] = b2v; binit[3] = b2v;
#pragma unroll
        for (int et = 0; et < 4; ++et) acc2[et][nt] = binit;
    }
#pragma unroll
    for (int ks2 = 0; ks2 < 2; ++ks2) {
        U4H8 wb[4];
#pragma unroll
        for (int nt = 0; nt < 4; ++nt)
            wb[nt].u = *(const uint4*)(w2t + (size_t)(nt * 16 + n15) * 32 + ks2 * 16 + q * 4);
#pragma unroll
        for (int et = 0; et < 4; ++et) {
            unsigned tmp[4];
#pragma unroll
            for (int jr = 0; jr < 4; ++jr) {
                int srcl = (2 * (q & 1) + (jr >> 1)) * 16 + n15;
                unsigned v0 = (unsigned)__shfl((int)psrc[2 * ks2][et][jr & 1], srcl, 64);
                unsigned v1 = (unsigned)__shfl((int)psrc[2 * ks2 + 1][et][jr & 1], srcl, 64);
                tmp[jr] = (q >> 1) ? v1 : v0;
            }
            U4H8 pf;
            pf.u.x = tmp[0]; pf.u.y = tmp[1]; pf.u.z = tmp[2]; pf.u.w = tmp[3];
#pragma unroll
            for (int nt = 0; nt < 4; ++nt)
                acc2[et][nt] = __builtin_amdgcn_mfma_f32_16x16x32_f16(
                    pf.h, wb[nt].h, acc2[et][nt], 0, 0, 0);
        }
    }

    // ---- epilogue: x += out, refresh xh; via LDS, two column halves ----
#pragma unroll
    for (int hf = 0; hf < 2; ++hf) {
#pragma unroll
        for (int et = 0; et < 4; ++et)
#pragma unroll
            for (int t2 = 0; t2 < 2; ++t2) {
                int nt = 2 * hf + t2;
                int cl = t2 * 16 + n15;
                int eb = et * 16 + q * 4;
#pragma unroll
                for (int r = 0; r < 4; ++r)
                    Mbuf[(eb + r) * 33 + cl] = acc2[et][nt][r];
            }
        __syncthreads();
        {
            int node = nbase + lane;
            if (node < NN) {
                float* xr = x + ((size_t)node << 6) + hf * 32;
                unsigned* xhp = xh + ((size_t)node << 5) + hf * 16;
#pragma unroll
                for (int p = 0; p < 16; ++p) {
                    float v0 = xr[2*p]     + Mbuf[lane * 33 + 2*p];
                    float v1 = xr[2*p + 1] + Mbuf[lane * 33 + 2*p + 1];
                    xr[2*p] = v0; xr[2*p + 1] = v1;
                    xhp[p] = pk2(v0, v1);
                }
            }
        }
        __syncthreads();
    }
}

// One thread per node; per-block LDS partial energy sums, then <=64
// global atomics per block (fixes same-line atomic serialization).
__global__ __launch_bounds__(256) void head_k(
    const float* __restrict__ x,
    const float* __restrict__ w1, const float* __restrict__ b1,
    const float* __restrict__ w2, const float* __restrict__ b2,
    const int* __restrict__ batch, float* __restrict__ energy)
{
    __shared__ float w1s[64 * 64];  // 16 KB
    __shared__ float esum[NGRAPH];
    for (int i = threadIdx.x; i < 64 * 64; i += 256) w1s[i] = w1[i];
    if (threadIdx.x < NGRAPH) esum[threadIdx.x] = 0.0f;
    __syncthreads();

    int n = blockIdx.x * 256 + threadIdx.x;
    if (n < NN) {
        float h[HH];
#pragma unroll
        for (int j = 0; j < HH; ++j) h[j] = b1[j];

        const float4* xi = (const float4*)(x + ((size_t)n << 6));
        for (int i4 = 0; i4 < 16; ++i4) {
            float4 v = xi[i4];
            const float* w = w1s + i4 * 4 * HH;
#pragma unroll
            for (int j = 0; j < HH; ++j) h[j] = fmaf(v.x, w[j], h[j]);
#pragma unroll
            for (int j = 0; j < HH; ++j) h[j] = fmaf(v.y, w[HH + j], h[j]);
#pragma unroll
            for (int j = 0; j < HH; ++j) h[j] = fmaf(v.z, w[2*HH + j], h[j]);
#pragma unroll
            for (int j = 0; j < HH; ++j) h[j] = fmaf(v.w, w[3*HH + j], h[j]);
        }

        float e = b2[0];
#pragma unroll
        for (int k = 0; k < HH; ++k) e = fmaf(silu_f(h[k]), w2[k], e);

        atomicAdd(&esum[batch[n]], e);
    }
    __syncthreads();
    if (threadIdx.x < NGRAPH) {
        float v = esum[threadIdx.x];
        if (v != 0.0f) atomicAdd(energy + threadIdx.x, v);
    }
}

extern "C" void kernel_launch(void* const* d_in, const int* in_sizes, int n_in,
                              void* d_out, int out_size, void* d_ws, size_t ws_size,
                              hipStream_t stream) {
    const int*   z       = (const int*)  d_in[0];
    const float* pos     = (const float*)d_in[1];
    const int*   eidx    = (const int*)  d_in[2];
    const int*   batch   = (const int*)  d_in[3];
    const float* embed   = (const float*)d_in[4];
    const float* msg_w1  = (const float*)d_in[5];   // (NL, 136, 64)
    const float* msg_b1  = (const float*)d_in[6];   // (NL, 64)
    const float* msg_w2  = (const float*)d_in[7];   // (NL, 64, 64)
    const float* msg_b2  = (const float*)d_in[8];   // (NL, 64)
    const float* upd_w1  = (const float*)d_in[9];   // (NL, 128, 64)
    const float* upd_b1  = (const float*)d_in[10];  // (NL, 64)
    const float* upd_w2  = (const float*)d_in[11];  // (NL, 64, 64)
    const float* upd_b2  = (const float*)d_in[12];  // (NL, 64)
    const float* eh_w1   = (const float*)d_in[13];  // (64, 64)
    const float* eh_b1   = (const float*)d_in[14];  // (64,)
    const float* eh_w2   = (const float*)d_in[15];  // (64, 1)
    const float* eh_b2   = (const float*)d_in[16];  // (1,)

    const int* erow = eidx;
    const int* ecol = eidx + EE;

    // ws layout (4-byte units)
    float*    x      = (float*)d_ws;                      // NN*64
    float*    agg    = x + (size_t)NN * HH;               // NN*64
    unsigned* xh     = (unsigned*)(agg + (size_t)NN * HH);// NN*32
    int*      deg    = (int*)(xh + (size_t)NN * 32);      // NN
    int*      cursor = deg + NN;                          // NN
    int*      bsum   = cursor + NN;                       // 64
    int*      perm   = bsum + 64;                         // EE
    unsigned* w1t    = (unsigned*)(perm + EE);            // NL*64*80
    unsigned* w2t    = w1t + NLAYER * 64 * 80;            // NL*64*32
    unsigned* w1tu   = w2t + NLAYER * 64 * 32;            // NL*64*64
    unsigned* w2tu   = w1tu + NLAYER * 64 * 64;           // NL*64*32
    float*    energy = (float*)d_out;

    (void)hipMemsetAsync(energy, 0, NGRAPH * sizeof(float), stream);
    (void)hipMemsetAsync(deg, 0, NN * sizeof(int), stream);

    embed_gather_k<<<(NN * 32 + 255) / 256, 256, 0, stream>>>(z, embed, x, xh);
    pack_w1t_k<<<(NLAYER * 64 * 80 + 255) / 256, 256, 0, stream>>>(msg_w1, w1t);
    pack_w2t_k<<<(NLAYER * 64 * 32 + 255) / 256, 256, 0, stream>>>(msg_w2, w2t);
    pack_uw1t_k<<<(NLAYER * 64 * 64 + 255) / 256, 256, 0, stream>>>(upd_w1, w1tu);
    pack_uw2t_k<<<(NLAYER * 64 * 32 + 255) / 256, 256, 0, stream>>>(upd_w2, w2tu);

    // CSR permutation (edges sorted by col)
    deg_k<<<(EE + 255) / 256, 256, 0, stream>>>(ecol, deg);
    scan1_k<<<NBLK1, 1024, 0, stream>>>(deg, cursor, bsum);
    scan2_k<<<1, 64, 0, stream>>>(bsum);
    scan3_k<<<(NN + 255) / 256, 256, 0, stream>>>(cursor, bsum);
    scatter_k<<<(EE + 255) / 256, 256, 0, stream>>>(ecol, cursor, perm);

    for (int l = 0; l < NLAYER; ++l) {
        (void)hipMemsetAsync(agg, 0, (size_t)NN * HH * sizeof(float), stream);
        msg_k<<<EE / 64, 64, 0, stream>>>(
            pos, erow, ecol, perm, xh,
            w1t + (size_t)l * 64 * 80,
            msg_b1 + (size_t)l * HH,
            w2t + (size_t)l * 64 * 32,
            msg_b2 + (size_t)l * HH,
            agg);
        upd_k<<<(NN + 63) / 64, 64, 0, stream>>>(
            x, xh, agg,
            w1tu + (size_t)l * 64 * 64,
            upd_b1 + (size_t)l * HH,
            w2tu + (size_t)l * 64 * 32,
            upd_b2 + (size_t)l * HH);
    }

    head_k<<<(NN + 255) / 256, 256, 0, stream>>>(
        x, eh_w1, eh_b1, eh_w2, eh_b2, batch, energy);
}

// Round 8
// 413.542 us; speedup vs baseline: 15.2178x; 1.1458x over previous
//
#include <hip/hip_runtime.h>
#include <math.h>

#define NN 50000
#define EE 800000
#define HH 64
#define NBASIS 8
#define NLAYER 2
#define NGRAPH 64
#define NBLK1 49  // ceil(NN/1024)

using half2_t = decltype(__builtin_amdgcn_cvt_pkrtz(0.0f, 0.0f));
typedef _Float16 f16x8 __attribute__((ext_vector_type(8)));
typedef float f32x4 __attribute__((ext_vector_type(4)));

union U4H8 { uint4 u; f16x8 h; };

__device__ __forceinline__ float silu_f(float v) {
    return v * (1.0f / (1.0f + __expf(-v)));
}

__device__ __forceinline__ unsigned pk2(float a, float b) {
    union { half2_t h; unsigned u; } x;
    x.h = __builtin_amdgcn_cvt_pkrtz(a, b);
    return x.u;
}

// gather embed -> x (fp32) and x_h (f16 pairs). idx over NN*32 pairs.
__global__ __launch_bounds__(256) void embed_gather_k(
    const int* __restrict__ z, const float* __restrict__ embed,
    float* __restrict__ x, unsigned* __restrict__ xh)
{
    int idx = blockIdx.x * 256 + threadIdx.x;
    if (idx >= NN * 32) return;
    int n = idx >> 5;
    int p = idx & 31;
    const float2* er = (const float2*)(embed + ((size_t)z[n] << 6));
    float2 v = er[p];
    ((float2*)x)[idx] = v;
    xh[idx] = pk2(v.x, v.y);
}

// ---- all weight prepacks fused: W^T f16-pair layouts ----
// w1t  [l][feat 64][kp 80 (pad from 68)]   msg W1
// w2t  [l][n 64][kp 32]                    msg W2
// w1tu [l][feat 64][kp 64]                 upd W1
// w2tu [l][n 64][kp 32]                    upd W2
// ehw1t[feat 64][kp 32]                    head W1
__global__ __launch_bounds__(256) void pack_all_k(
    const float* __restrict__ msg_w1, const float* __restrict__ msg_w2,
    const float* __restrict__ upd_w1, const float* __restrict__ upd_w2,
    const float* __restrict__ eh_w1,
    unsigned* __restrict__ w1t, unsigned* __restrict__ w2t,
    unsigned* __restrict__ w1tu, unsigned* __restrict__ w2tu,
    unsigned* __restrict__ ehw1t)
{
    int idx = blockIdx.x * 256 + threadIdx.x;
    if (idx < 10240) {                    // msg w1t
        int l = idx / 5120, rem = idx % 5120;
        int f = rem / 80, kp = rem % 80;
        const float* w = msg_w1 + (size_t)l * 136 * 64;
        unsigned v = 0;
        if (kp < 68) v = pk2(w[(2*kp)*64 + f], w[(2*kp+1)*64 + f]);
        w1t[idx] = v;
    } else if (idx < 14336) {             // msg w2t
        int j = idx - 10240;
        int l = j / 2048, rem = j % 2048;
        int n = rem / 32, kp = rem % 32;
        const float* w = msg_w2 + (size_t)l * 64 * 64;
        w2t[j] = pk2(w[(2*kp)*64 + n], w[(2*kp+1)*64 + n]);
    } else if (idx < 22528) {             // upd w1tu
        int j = idx - 14336;
        int l = j / 4096, rem = j % 4096;
        int f = rem >> 6, kp = rem & 63;
        const float* w = upd_w1 + (size_t)l * 128 * 64;
        w1tu[j] = pk2(w[(2*kp)*64 + f], w[(2*kp+1)*64 + f]);
    } else if (idx < 26624) {             // upd w2tu
        int j = idx - 22528;
        int l = j / 2048, rem = j % 2048;
        int n = rem / 32, kp = rem % 32;
        const float* w = upd_w2 + (size_t)l * 64 * 64;
        w2tu[j] = pk2(w[(2*kp)*64 + n], w[(2*kp+1)*64 + n]);
    } else if (idx < 28672) {             // head ehw1t
        int j = idx - 26624;
        int f = j / 32, kp = j % 32;
        ehw1t[j] = pk2(eh_w1[(2*kp)*64 + f], eh_w1[(2*kp+1)*64 + f]);
    }
}

// ---- CSR build ----
__global__ __launch_bounds__(256) void deg_k(
    const int* __restrict__ ecol, int* __restrict__ deg)
{
    int e = blockIdx.x * 256 + threadIdx.x;
    if (e < EE) atomicAdd(&deg[ecol[e]], 1);
}

__global__ __launch_bounds__(1024) void scan1_k(
    const int* __restrict__ deg, int* __restrict__ cursor,
    int* __restrict__ bsum)
{
    __shared__ int wsum[16];
    int t = threadIdx.x, lane = t & 63, wave = t >> 6;
    int i = blockIdx.x * 1024 + t;
    int v = (i < NN) ? deg[i] : 0;
    int s = v;
#pragma unroll
    for (int off = 1; off < 64; off <<= 1) {
        int tv = __shfl_up(s, off, 64);
        if (lane >= off) s += tv;
    }
    if (lane == 63) wsum[wave] = s;
    __syncthreads();
    if (wave == 0) {
        int ws = (lane < 16) ? wsum[lane] : 0;
        int ss = ws;
#pragma unroll
        for (int off = 1; off < 16; off <<= 1) {
            int tv = __shfl_up(ss, off, 64);
            if (lane >= off) ss += tv;
        }
        if (lane < 16) wsum[lane] = ss - ws;
    }
    __syncthreads();
    int excl = wsum[wave] + s - v;
    if (i < NN) cursor[i] = excl;     // block-local exclusive scan
    if (t == 1023) bsum[blockIdx.x] = excl + v;
}

__global__ __launch_bounds__(64) void scan2_k(int* __restrict__ bsum)
{
    int lane = threadIdx.x;
    int v = (lane < NBLK1) ? bsum[lane] : 0;
    int s = v;
#pragma unroll
    for (int off = 1; off < 64; off <<= 1) {
        int tv = __shfl_up(s, off, 64);
        if (lane >= off) s += tv;
    }
    if (lane < NBLK1) bsum[lane] = s - v;
}

// scatter: slot = local-scan + block offset; write SORTED edge arrays
// rowS/colS plus precomputed distance dS (kills msg_k's random gathers).
__global__ __launch_bounds__(256) void scatter_k(
    const int* __restrict__ erow, const int* __restrict__ ecol,
    const float* __restrict__ pos,
    int* __restrict__ cursor, const int* __restrict__ bsum,
    int* __restrict__ rowS, int* __restrict__ colS, float* __restrict__ dS)
{
    int e = blockIdx.x * 256 + threadIdx.x;
    if (e >= EE) return;
    int c = ecol[e], r = erow[e];
    int slot = atomicAdd(&cursor[c], 1) + bsum[c >> 10];
    rowS[slot] = r;
    colS[slot] = c;
    float dx = pos[3*r]   - pos[3*c];
    float dy = pos[3*r+1] - pos[3*c+1];
    float dz = pos[3*r+2] - pos[3*c+2];
    dS[slot] = sqrtf(dx*dx + dy*dy + dz*dz);
}

// MFMA msg kernel: one wave per 64 sorted edges. Frags streamed in the
// K-loop to cut register peak; (64,3) caps unified VGPR+AGPR for 3 waves/EU.
__global__ __launch_bounds__(64, 3) void msg_k(
    const float* __restrict__ dS,
    const int* __restrict__ rowS, const int* __restrict__ colS,
    const unsigned* __restrict__ xh,
    const unsigned* __restrict__ w1t, const float* __restrict__ b1,
    const unsigned* __restrict__ w2t, const float* __restrict__ b2,
    float* __restrict__ agg)
{
    __shared__ __align__(16) unsigned earr[64 * 4];  // 64 edges x 8 f16
    __shared__ int ckey_s[64];
    __shared__ float Mbuf[64 * 33];

    const int lane = threadIdx.x;
    const int q = lane >> 4, n15 = lane & 15;
    const size_t base = (size_t)blockIdx.x * 64;     // EE % 64 == 0

    // ---- per-edge prep (d precomputed; coalesced reads) ----
    {
        float d = dS[base + lane];
        ckey_s[lane] = colS[base + lane];
        float env = 0.0f;
        if (d < 5.0f) {
            float cv = __cosf(d * 0.31415926535897932f);  // pi/(2*CUTOFF)
            env = cv * cv;
        }
        float scale = (d > 0.0f) ? (env / d) : env;
        float ea[NBASIS];
#pragma unroll
        for (int k = 0; k < NBASIS; ++k)
            ea[k] = __sinf((float)(k + 1) * 0.62831853071795865f * d) * scale;
#pragma unroll
        for (int p = 0; p < 4; ++p)
            earr[lane * 4 + p] = pk2(ea[2*p], ea[2*p+1]);
    }
    __syncthreads();

    // gather keys for this lane's B-columns (coalesced broadcasty reads)
    int cn[4], rn[4];
#pragma unroll
    for (int nt = 0; nt < 4; ++nt) {
        int eB = nt * 16 + n15;
        cn[nt] = ckey_s[eB];
        rn[nt] = rowS[base + eB];
    }

    // ---- GEMM1, frags streamed per ks ----
    f32x4 acc1[4][4];
#pragma unroll
    for (int mt = 0; mt < 4; ++mt) {
        f32x4 binit = *(const f32x4*)(b1 + mt * 16 + q * 4);
#pragma unroll
        for (int nt = 0; nt < 4; ++nt) acc1[mt][nt] = binit;
    }
#pragma unroll
    for (int ks = 0; ks < 5; ++ks) {
        U4H8 bfk[4];
#pragma unroll
        for (int nt = 0; nt < 4; ++nt) {
            if (ks == 4) {
                uint4 zz; zz.x = zz.y = zz.z = zz.w = 0;
                bfk[nt].u = (q == 0) ? *(const uint4*)(earr + (nt * 16 + n15) * 4) : zz;
            } else if (ks < 2) {
                bfk[nt].u = ((const uint4*)(xh + ((size_t)cn[nt] << 5)))[ks * 4 + q];
            } else {
                bfk[nt].u = ((const uint4*)(xh + ((size_t)rn[nt] << 5)))[(ks - 2) * 4 + q];
            }
        }
#pragma unroll
        for (int mt = 0; mt < 4; ++mt) {
            U4H8 af;
            af.u = *(const uint4*)(w1t + (size_t)(mt * 16 + n15) * 80 + ks * 16 + q * 4);
#pragma unroll
            for (int nt = 0; nt < 4; ++nt)
                acc1[mt][nt] = __builtin_amdgcn_mfma_f32_16x16x32_f16(
                    af.h, bfk[nt].h, acc1[mt][nt], 0, 0, 0);
        }
    }

    // ---- silu + pack ----
    unsigned psrc[4][4][2];
#pragma unroll
    for (int mt = 0; mt < 4; ++mt)
#pragma unroll
        for (int nt = 0; nt < 4; ++nt) {
            psrc[mt][nt][0] = pk2(silu_f(acc1[mt][nt][0]), silu_f(acc1[mt][nt][1]));
            psrc[mt][nt][1] = pk2(silu_f(acc1[mt][nt][2]), silu_f(acc1[mt][nt][3]));
        }

    // ---- GEMM2 ----
    f32x4 acc2[4][4];
#pragma unroll
    for (int nt = 0; nt < 4; ++nt) {
        float b2v = b2[nt * 16 + n15];
        f32x4 binit; binit[0] = b2v; binit[1] = b2v; binit[2] = b2v; binit[3] = b2v;
#pragma unroll
        for (int et = 0; et < 4; ++et) acc2[et][nt] = binit;
    }
#pragma unroll
    for (int ks2 = 0; ks2 < 2; ++ks2) {
        U4H8 wb[4];
#pragma unroll
        for (int nt = 0; nt < 4; ++nt)
            wb[nt].u = *(const uint4*)(w2t + (size_t)(nt * 16 + n15) * 32 + ks2 * 16 + q * 4);
#pragma unroll
        for (int et = 0; et < 4; ++et) {
            unsigned tmp[4];
#pragma unroll
            for (int jr = 0; jr < 4; ++jr) {
                int srcl = (2 * (q & 1) + (jr >> 1)) * 16 + n15;
                unsigned v0 = (unsigned)__shfl((int)psrc[2 * ks2][et][jr & 1], srcl, 64);
                unsigned v1 = (unsigned)__shfl((int)psrc[2 * ks2 + 1][et][jr & 1], srcl, 64);
                tmp[jr] = (q >> 1) ? v1 : v0;
            }
            U4H8 pf;
            pf.u.x = tmp[0]; pf.u.y = tmp[1]; pf.u.z = tmp[2]; pf.u.w = tmp[3];
#pragma unroll
            for (int nt = 0; nt < 4; ++nt)
                acc2[et][nt] = __builtin_amdgcn_mfma_f32_16x16x32_f16(
                    pf.h, wb[nt].h, acc2[et][nt], 0, 0, 0);
        }
    }

    // ---- segmented reduce over edges, two column-halves through LDS ----
#pragma unroll
    for (int hf = 0; hf < 2; ++hf) {
#pragma unroll
        for (int et = 0; et < 4; ++et)
#pragma unroll
            for (int t2 = 0; t2 < 2; ++t2) {
                int nt = 2 * hf + t2;
                int cl = t2 * 16 + n15;
                int eb = et * 16 + q * 4;
#pragma unroll
                for (int r = 0; r < 4; ++r)
                    Mbuf[(eb + r) * 33 + cl] = acc2[et][nt][r];
            }
        __syncthreads();
        {
            int cl = lane & 31, st = lane >> 5;
            int ebase = 32 * st;
            float run = 0.0f;
            int runkey = ckey_s[ebase];
            bool atstart = true;
#pragma unroll
            for (int i = 0; i < 32; ++i) {
                int kk = ckey_s[ebase + i];
                float v = Mbuf[(ebase + i) * 33 + cl];
                if (kk != runkey) {
                    float* dst = agg + ((size_t)runkey << 6) + hf * 32 + cl;
                    if (atstart) atomicAdd(dst, run); else *dst = run;
                    run = 0.0f; runkey = kk; atstart = false;
                }
                run += v;
            }
            atomicAdd(agg + ((size_t)runkey << 6) + hf * 32 + cl, run);
        }
        __syncthreads();
    }
}

// MFMA upd kernel: one wave per 64 nodes; frags streamed per ks.
__global__ __launch_bounds__(64) void upd_k(
    float* __restrict__ x, unsigned* __restrict__ xh,
    const float* __restrict__ agg,
    const unsigned* __restrict__ w1t, const float* __restrict__ b1,
    const unsigned* __restrict__ w2t, const float* __restrict__ b2)
{
    __shared__ float Mbuf[64 * 33];

    const int lane = threadIdx.x;
    const int q = lane >> 4, n15 = lane & 15;
    const int nbase = blockIdx.x * 64;

    int nc[4];
#pragma unroll
    for (int nt = 0; nt < 4; ++nt) {
        int node = nbase + nt * 16 + n15;
        nc[nt] = (node < NN) ? node : (NN - 1);
    }

    f32x4 acc1[4][4];
#pragma unroll
    for (int mt = 0; mt < 4; ++mt) {
        f32x4 binit = *(const f32x4*)(b1 + mt * 16 + q * 4);
#pragma unroll
        for (int nt = 0; nt < 4; ++nt) acc1[mt][nt] = binit;
    }
#pragma unroll
    for (int ks = 0; ks < 4; ++ks) {
        U4H8 bfk[4];
#pragma unroll
        for (int nt = 0; nt < 4; ++nt) {
            if (ks < 2) {
                bfk[nt].u = ((const uint4*)(xh + ((size_t)nc[nt] << 5)))[ks * 4 + q];
            } else {
                const float4* ap = (const float4*)(agg + ((size_t)nc[nt] << 6));
                int o = (ks - 2) * 8 + 2 * q;
                float4 a0 = ap[o], a1 = ap[o + 1];
                bfk[nt].u.x = pk2(a0.x, a0.y); bfk[nt].u.y = pk2(a0.z, a0.w);
                bfk[nt].u.z = pk2(a1.x, a1.y); bfk[nt].u.w = pk2(a1.z, a1.w);
            }
        }
#pragma unroll
        for (int mt = 0; mt < 4; ++mt) {
            U4H8 af;
            af.u = *(const uint4*)(w1t + (size_t)(mt * 16 + n15) * 64 + ks * 16 + q * 4);
#pragma unroll
            for (int nt = 0; nt < 4; ++nt)
                acc1[mt][nt] = __builtin_amdgcn_mfma_f32_16x16x32_f16(
                    af.h, bfk[nt].h, acc1[mt][nt], 0, 0, 0);
        }
    }

    unsigned psrc[4][4][2];
#pragma unroll
    for (int mt = 0; mt < 4; ++mt)
#pragma unroll
        for (int nt = 0; nt < 4; ++nt) {
            psrc[mt][nt][0] = pk2(silu_f(acc1[mt][nt][0]), silu_f(acc1[mt][nt][1]));
            psrc[mt][nt][1] = pk2(silu_f(acc1[mt][nt][2]), silu_f(acc1[mt][nt][3]));
        }

    f32x4 acc2[4][4];
#pragma unroll
    for (int nt = 0; nt < 4; ++nt) {
        float b2v = b2[nt * 16 + n15];
        f32x4 binit; binit[0] = b2v; binit[1] = b2v; binit[2] = b2v; binit[3] = b2v;
#pragma unroll
        for (int et = 0; et < 4; ++et) acc2[et][nt] = binit;
    }
#pragma unroll
    for (int ks2 = 0; ks2 < 2; ++ks2) {
        U4H8 wb[4];
#pragma unroll
        for (int nt = 0; nt < 4; ++nt)
            wb[nt].u = *(const uint4*)(w2t + (size_t)(nt * 16 + n15) * 32 + ks2 * 16 + q * 4);
#pragma unroll
        for (int et = 0; et < 4; ++et) {
            unsigned tmp[4];
#pragma unroll
            for (int jr = 0; jr < 4; ++jr) {
                int srcl = (2 * (q & 1) + (jr >> 1)) * 16 + n15;
                unsigned v0 = (unsigned)__shfl((int)psrc[2 * ks2][et][jr & 1], srcl, 64);
                unsigned v1 = (unsigned)__shfl((int)psrc[2 * ks2 + 1][et][jr & 1], srcl, 64);
                tmp[jr] = (q >> 1) ? v1 : v0;
            }
            U4H8 pf;
            pf.u.x = tmp[0]; pf.u.y = tmp[1]; pf.u.z = tmp[2]; pf.u.w = tmp[3];
#pragma unroll
            for (int nt = 0; nt < 4; ++nt)
                acc2[et][nt] = __builtin_amdgcn_mfma_f32_16x16x32_f16(
                    pf.h, wb[nt].h, acc2[et][nt], 0, 0, 0);
        }
    }

#pragma unroll
    for (int hf = 0; hf < 2; ++hf) {
#pragma unroll
        for (int et = 0; et < 4; ++et)
#pragma unroll
            for (int t2 = 0; t2 < 2; ++t2) {
                int nt = 2 * hf + t2;
                int cl = t2 * 16 + n15;
                int eb = et * 16 + q * 4;
#pragma unroll
                for (int r = 0; r < 4; ++r)
                    Mbuf[(eb + r) * 33 + cl] = acc2[et][nt][r];
            }
        __syncthreads();
        {
            int node = nbase + lane;
            if (node < NN) {
                float* xr = x + ((size_t)node << 6) + hf * 32;
                unsigned* xhp = xh + ((size_t)node << 5) + hf * 16;
#pragma unroll
                for (int p = 0; p < 16; ++p) {
                    float v0 = xr[2*p]     + Mbuf[lane * 33 + 2*p];
                    float v1 = xr[2*p + 1] + Mbuf[lane * 33 + 2*p + 1];
                    xr[2*p] = v0; xr[2*p + 1] = v1;
                    xhp[p] = pk2(v0, v1);
                }
            }
        }
        __syncthreads();
    }
}

// MFMA head kernel: one wave per 64 nodes. GEMM1 (K=64) then shuffle-dot
// with eh_w2, per-block LDS batch sums, few global atomics.
__global__ __launch_bounds__(64) void head_k(
    const unsigned* __restrict__ xh,
    const unsigned* __restrict__ w1t, const float* __restrict__ b1,
    const float* __restrict__ w2, const float* __restrict__ b2,
    const int* __restrict__ batch, float* __restrict__ energy)
{
    __shared__ float esum[NGRAPH];

    const int lane = threadIdx.x;
    const int q = lane >> 4, n15 = lane & 15;
    const int nbase = blockIdx.x * 64;

    esum[lane] = 0.0f;
    __syncthreads();

    int nc[4];
#pragma unroll
    for (int nt = 0; nt < 4; ++nt) {
        int node = nbase + nt * 16 + n15;
        nc[nt] = (node < NN) ? node : (NN - 1);
    }

    f32x4 acc[4][4];
#pragma unroll
    for (int mt = 0; mt < 4; ++mt) {
        f32x4 binit = *(const f32x4*)(b1 + mt * 16 + q * 4);
#pragma unroll
        for (int nt = 0; nt < 4; ++nt) acc[mt][nt] = binit;
    }
#pragma unroll
    for (int ks = 0; ks < 2; ++ks) {
        U4H8 bfk[4];
#pragma unroll
        for (int nt = 0; nt < 4; ++nt)
            bfk[nt].u = ((const uint4*)(xh + ((size_t)nc[nt] << 5)))[ks * 4 + q];
#pragma unroll
        for (int mt = 0; mt < 4; ++mt) {
            U4H8 af;
            af.u = *(const uint4*)(w1t + (size_t)(mt * 16 + n15) * 32 + ks * 16 + q * 4);
#pragma unroll
            for (int nt = 0; nt < 4; ++nt)
                acc[mt][nt] = __builtin_amdgcn_mfma_f32_16x16x32_f16(
                    af.h, bfk[nt].h, acc[mt][nt], 0, 0, 0);
        }
    }

    // dot with w2 over feats (rows), reduce across q lanes
    f32x4 wv[4];
#pragma unroll
    for (int mt = 0; mt < 4; ++mt) wv[mt] = *(const f32x4*)(w2 + mt * 16 + q * 4);
    float b2v = b2[0];
#pragma unroll
    for (int nt = 0; nt < 4; ++nt) {
        float e = 0.0f;
#pragma unroll
        for (int mt = 0; mt < 4; ++mt)
#pragma unroll
            for (int r = 0; r < 4; ++r)
                e = fmaf(silu_f(acc[mt][nt][r]), wv[mt][r], e);
        e += __shfl_xor(e, 16, 64);
        e += __shfl_xor(e, 32, 64);
        if (q == 0) {
            int node = nbase + nt * 16 + n15;
            if (node < NN) atomicAdd(&esum[batch[node]], e + b2v);
        }
    }
    __syncthreads();
    float v = esum[lane];
    if (v != 0.0f) atomicAdd(energy + lane, v);
}

extern "C" void kernel_launch(void* const* d_in, const int* in_sizes, int n_in,
                              void* d_out, int out_size, void* d_ws, size_t ws_size,
                              hipStream_t stream) {
    const int*   z       = (const int*)  d_in[0];
    const float* pos     = (const float*)d_in[1];
    const int*   eidx    = (const int*)  d_in[2];
    const int*   batch   = (const int*)  d_in[3];
    const float* embed   = (const float*)d_in[4];
    const float* msg_w1  = (const float*)d_in[5];   // (NL, 136, 64)
    const float* msg_b1  = (const float*)d_in[6];   // (NL, 64)
    const float* msg_w2  = (const float*)d_in[7];   // (NL, 64, 64)
    const float* msg_b2  = (const float*)d_in[8];   // (NL, 64)
    const float* upd_w1  = (const float*)d_in[9];   // (NL, 128, 64)
    const float* upd_b1  = (const float*)d_in[10];  // (NL, 64)
    const float* upd_w2  = (const float*)d_in[11];  // (NL, 64, 64)
    const float* upd_b2  = (const float*)d_in[12];  // (NL, 64)
    const float* eh_w1   = (const float*)d_in[13];  // (64, 64)
    const float* eh_b1   = (const float*)d_in[14];  // (64,)
    const float* eh_w2   = (const float*)d_in[15];  // (64, 1)
    const float* eh_b2   = (const float*)d_in[16];  // (1,)

    const int* erow = eidx;
    const int* ecol = eidx + EE;

    // ws layout (4-byte units)
    float*    x      = (float*)d_ws;                      // NN*64
    float*    agg    = x + (size_t)NN * HH;               // NN*64
    unsigned* xh     = (unsigned*)(agg + (size_t)NN * HH);// NN*32
    int*      deg    = (int*)(xh + (size_t)NN * 32);      // NN
    int*      cursor = deg + NN;                          // NN
    int*      bsum   = cursor + NN;                       // 64
    int*      rowS   = bsum + 64;                         // EE
    int*      colS   = rowS + EE;                         // EE
    float*    dS     = (float*)(colS + EE);               // EE
    unsigned* w1t    = (unsigned*)(dS + EE);              // NL*64*80 = 10240
    unsigned* w2t    = w1t + NLAYER * 64 * 80;            // NL*64*32 = 4096
    unsigned* w1tu   = w2t + NLAYER * 64 * 32;            // NL*64*64 = 8192
    unsigned* w2tu   = w1tu + NLAYER * 64 * 64;           // NL*64*32 = 4096
    unsigned* ehw1t  = w2tu + NLAYER * 64 * 32;           // 64*32   = 2048
    float*    energy = (float*)d_out;

    (void)hipMemsetAsync(energy, 0, NGRAPH * sizeof(float), stream);
    (void)hipMemsetAsync(deg, 0, NN * sizeof(int), stream);

    embed_gather_k<<<(NN * 32 + 255) / 256, 256, 0, stream>>>(z, embed, x, xh);
    pack_all_k<<<112, 256, 0, stream>>>(msg_w1, msg_w2, upd_w1, upd_w2, eh_w1,
                                        w1t, w2t, w1tu, w2tu, ehw1t);

    // CSR permutation (edges sorted by col) + precomputed d
    deg_k<<<(EE + 255) / 256, 256, 0, stream>>>(ecol, deg);
    scan1_k<<<NBLK1, 1024, 0, stream>>>(deg, cursor, bsum);
    scan2_k<<<1, 64, 0, stream>>>(bsum);
    scatter_k<<<(EE + 255) / 256, 256, 0, stream>>>(
        erow, ecol, pos, cursor, bsum, rowS, colS, dS);

    for (int l = 0; l < NLAYER; ++l) {
        (void)hipMemsetAsync(agg, 0, (size_t)NN * HH * sizeof(float), stream);
        msg_k<<<EE / 64, 64, 0, stream>>>(
            dS, rowS, colS, xh,
            w1t + (size_t)l * 64 * 80,
            msg_b1 + (size_t)l * HH,
            w2t + (size_t)l * 64 * 32,
            msg_b2 + (size_t)l * HH,
            agg);
        upd_k<<<(NN + 63) / 64, 64, 0, stream>>>(
            x, xh, agg,
            w1tu + (size_t)l * 64 * 64,
            upd_b1 + (size_t)l * HH,
            w2tu + (size_t)l * 64 * 32,
            upd_b2 + (size_t)l * HH);
    }

    head_k<<<(NN + 63) / 64, 64, 0, stream>>>(
        xh, ehw1t, eh_b1, eh_w2, eh_b2, batch, energy);
}

// Round 9
// 401.318 us; speedup vs baseline: 15.6814x; 1.0305x over previous
//
#include <hip/hip_runtime.h>
#include <math.h>

#define NN 50000
#define EE 800000
#define HH 64
#define NBASIS 8
#define NLAYER 2
#define NGRAPH 64
#define NBLK1 49  // ceil(NN/1024)

using half2_t = decltype(__builtin_amdgcn_cvt_pkrtz(0.0f, 0.0f));
typedef _Float16 f16x8 __attribute__((ext_vector_type(8)));
typedef float f32x4 __attribute__((ext_vector_type(4)));

union U4H8 { uint4 u; f16x8 h; };

__device__ __forceinline__ float silu_f(float v) {
    return v * (1.0f / (1.0f + __expf(-v)));
}

__device__ __forceinline__ unsigned pk2(float a, float b) {
    union { half2_t h; unsigned u; } x;
    x.h = __builtin_amdgcn_cvt_pkrtz(a, b);
    return x.u;
}

// fused prep: embed gather (blocks 0..6249), weight prepack (6250..6361),
// degree count (6362..9486)
__global__ __launch_bounds__(256) void prep_k(
    const int* __restrict__ z, const float* __restrict__ embed,
    float* __restrict__ x, unsigned* __restrict__ xh,
    const float* __restrict__ msg_w1, const float* __restrict__ msg_w2,
    const float* __restrict__ upd_w1, const float* __restrict__ upd_w2,
    const float* __restrict__ eh_w1,
    unsigned* __restrict__ w1t, unsigned* __restrict__ w2t,
    unsigned* __restrict__ w1tu, unsigned* __restrict__ w2tu,
    unsigned* __restrict__ ehw1t,
    const int* __restrict__ ecol, int* __restrict__ deg)
{
    int b = blockIdx.x;
    if (b < 6250) {                       // embed gather: NN*32 pairs
        int idx = b * 256 + threadIdx.x;  // < 1,600,000 always
        int n = idx >> 5;
        int p = idx & 31;
        const float2* er = (const float2*)(embed + ((size_t)z[n] << 6));
        float2 v = er[p];
        ((float2*)x)[idx] = v;
        xh[idx] = pk2(v.x, v.y);
    } else if (b < 6362) {                // weight prepack, 28672 threads
        int idx = (b - 6250) * 256 + threadIdx.x;
        if (idx < 10240) {                    // msg w1t [l][f 64][kp 80]
            int l = idx / 5120, rem = idx % 5120;
            int f = rem / 80, kp = rem % 80;
            const float* w = msg_w1 + (size_t)l * 136 * 64;
            unsigned v = 0;
            if (kp < 68) v = pk2(w[(2*kp)*64 + f], w[(2*kp+1)*64 + f]);
            w1t[idx] = v;
        } else if (idx < 14336) {             // msg w2t [l][n 64][kp 32]
            int j = idx - 10240;
            int l = j / 2048, rem = j % 2048;
            int n = rem / 32, kp = rem % 32;
            const float* w = msg_w2 + (size_t)l * 64 * 64;
            w2t[j] = pk2(w[(2*kp)*64 + n], w[(2*kp+1)*64 + n]);
        } else if (idx < 22528) {             // upd w1tu [l][f 64][kp 64]
            int j = idx - 14336;
            int l = j / 4096, rem = j % 4096;
            int f = rem >> 6, kp = rem & 63;
            const float* w = upd_w1 + (size_t)l * 128 * 64;
            w1tu[j] = pk2(w[(2*kp)*64 + f], w[(2*kp+1)*64 + f]);
        } else if (idx < 26624) {             // upd w2tu [l][n 64][kp 32]
            int j = idx - 22528;
            int l = j / 2048, rem = j % 2048;
            int n = rem / 32, kp = rem % 32;
            const float* w = upd_w2 + (size_t)l * 64 * 64;
            w2tu[j] = pk2(w[(2*kp)*64 + n], w[(2*kp+1)*64 + n]);
        } else if (idx < 28672) {             // head ehw1t [f 64][kp 32]
            int j = idx - 26624;
            int f = j / 32, kp = j % 32;
            ehw1t[j] = pk2(eh_w1[(2*kp)*64 + f], eh_w1[(2*kp+1)*64 + f]);
        }
    } else {                              // degree count
        int e = (b - 6362) * 256 + threadIdx.x;
        if (e < EE) atomicAdd(&deg[ecol[e]], 1);
    }
}

__global__ __launch_bounds__(1024) void scan1_k(
    const int* __restrict__ deg, int* __restrict__ cursor,
    int* __restrict__ bsum)
{
    __shared__ int wsum[16];
    int t = threadIdx.x, lane = t & 63, wave = t >> 6;
    int i = blockIdx.x * 1024 + t;
    int v = (i < NN) ? deg[i] : 0;
    int s = v;
#pragma unroll
    for (int off = 1; off < 64; off <<= 1) {
        int tv = __shfl_up(s, off, 64);
        if (lane >= off) s += tv;
    }
    if (lane == 63) wsum[wave] = s;
    __syncthreads();
    if (wave == 0) {
        int ws = (lane < 16) ? wsum[lane] : 0;
        int ss = ws;
#pragma unroll
        for (int off = 1; off < 16; off <<= 1) {
            int tv = __shfl_up(ss, off, 64);
            if (lane >= off) ss += tv;
        }
        if (lane < 16) wsum[lane] = ss - ws;
    }
    __syncthreads();
    int excl = wsum[wave] + s - v;
    if (i < NN) cursor[i] = excl;     // block-local exclusive scan
    if (t == 1023) bsum[blockIdx.x] = excl + v;
}

__global__ __launch_bounds__(64) void scan2_k(int* __restrict__ bsum)
{
    int lane = threadIdx.x;
    int v = (lane < NBLK1) ? bsum[lane] : 0;
    int s = v;
#pragma unroll
    for (int off = 1; off < 64; off <<= 1) {
        int tv = __shfl_up(s, off, 64);
        if (lane >= off) s += tv;
    }
    if (lane < NBLK1) bsum[lane] = s - v;
}

// scatter: one interleaved uint4 {row, col, d_bits, 0} per sorted slot
// (1 random cache line per edge instead of 3)
__global__ __launch_bounds__(256) void scatter_k(
    const int* __restrict__ erow, const int* __restrict__ ecol,
    const float* __restrict__ pos,
    int* __restrict__ cursor, const int* __restrict__ bsum,
    uint4* __restrict__ edgeS)
{
    int e = blockIdx.x * 256 + threadIdx.x;
    if (e >= EE) return;
    int c = ecol[e], r = erow[e];
    int slot = atomicAdd(&cursor[c], 1) + bsum[c >> 10];
    float dx = pos[3*r]   - pos[3*c];
    float dy = pos[3*r+1] - pos[3*c+1];
    float dz = pos[3*r+2] - pos[3*c+2];
    float d = sqrtf(dx*dx + dy*dy + dz*dz);
    uint4 v;
    v.x = (unsigned)r; v.y = (unsigned)c;
    v.z = __float_as_uint(d); v.w = 0;
    edgeS[slot] = v;
}

// MFMA msg kernel: 256-thread blocks = 4 private waves, each handling 64
// sorted edges. LDS 39,936 B/block -> 4 blocks/CU = 16 waves/CU.
__global__ __launch_bounds__(256, 4) void msg_k(
    const uint4* __restrict__ edgeS,
    const unsigned* __restrict__ xh,
    const unsigned* __restrict__ w1t, const float* __restrict__ b1,
    const unsigned* __restrict__ w2t, const float* __restrict__ b2,
    float* __restrict__ agg)
{
    __shared__ __align__(16) unsigned earr[4][64 * 4];
    __shared__ int ckey_s[4][64];
    __shared__ int rkey_s[4][64];
    __shared__ float Mbuf[4][64 * 33];

    const int wid  = threadIdx.x >> 6;
    const int lane = threadIdx.x & 63;
    const int q = lane >> 4, n15 = lane & 15;
    const size_t base = (size_t)blockIdx.x * 256 + wid * 64;

    // ---- per-edge prep (single coalesced 16B read) ----
    {
        uint4 ev = edgeS[base + lane];
        rkey_s[wid][lane] = (int)ev.x;
        ckey_s[wid][lane] = (int)ev.y;
        float d = __uint_as_float(ev.z);
        float env = 0.0f;
        if (d < 5.0f) {
            float cv = __cosf(d * 0.31415926535897932f);  // pi/(2*CUTOFF)
            env = cv * cv;
        }
        float scale = (d > 0.0f) ? (env / d) : env;
        float ea[NBASIS];
#pragma unroll
        for (int k = 0; k < NBASIS; ++k)
            ea[k] = __sinf((float)(k + 1) * 0.62831853071795865f * d) * scale;
#pragma unroll
        for (int p = 0; p < 4; ++p)
            earr[wid][lane * 4 + p] = pk2(ea[2*p], ea[2*p+1]);
    }
    __syncthreads();

    int cn[4], rn[4];
#pragma unroll
    for (int nt = 0; nt < 4; ++nt) {
        int eB = nt * 16 + n15;
        cn[nt] = ckey_s[wid][eB];
        rn[nt] = rkey_s[wid][eB];
    }

    // ---- GEMM1, frags streamed per ks ----
    f32x4 acc1[4][4];
#pragma unroll
    for (int mt = 0; mt < 4; ++mt) {
        f32x4 binit = *(const f32x4*)(b1 + mt * 16 + q * 4);
#pragma unroll
        for (int nt = 0; nt < 4; ++nt) acc1[mt][nt] = binit;
    }
#pragma unroll
    for (int ks = 0; ks < 5; ++ks) {
        U4H8 bfk[4];
#pragma unroll
        for (int nt = 0; nt < 4; ++nt) {
            if (ks == 4) {
                uint4 zz; zz.x = zz.y = zz.z = zz.w = 0;
                bfk[nt].u = (q == 0) ? *(const uint4*)(earr[wid] + (nt * 16 + n15) * 4) : zz;
            } else if (ks < 2) {
                bfk[nt].u = ((const uint4*)(xh + ((size_t)cn[nt] << 5)))[ks * 4 + q];
            } else {
                bfk[nt].u = ((const uint4*)(xh + ((size_t)rn[nt] << 5)))[(ks - 2) * 4 + q];
            }
        }
#pragma unroll
        for (int mt = 0; mt < 4; ++mt) {
            U4H8 af;
            af.u = *(const uint4*)(w1t + (size_t)(mt * 16 + n15) * 80 + ks * 16 + q * 4);
#pragma unroll
            for (int nt = 0; nt < 4; ++nt)
                acc1[mt][nt] = __builtin_amdgcn_mfma_f32_16x16x32_f16(
                    af.h, bfk[nt].h, acc1[mt][nt], 0, 0, 0);
        }
    }

    // ---- silu + pack ----
    unsigned psrc[4][4][2];
#pragma unroll
    for (int mt = 0; mt < 4; ++mt)
#pragma unroll
        for (int nt = 0; nt < 4; ++nt) {
            psrc[mt][nt][0] = pk2(silu_f(acc1[mt][nt][0]), silu_f(acc1[mt][nt][1]));
            psrc[mt][nt][1] = pk2(silu_f(acc1[mt][nt][2]), silu_f(acc1[mt][nt][3]));
        }

    // ---- GEMM2 ----
    f32x4 acc2[4][4];
#pragma unroll
    for (int nt = 0; nt < 4; ++nt) {
        float b2v = b2[nt * 16 + n15];
        f32x4 binit; binit[0] = b2v; binit[1] = b2v; binit[2] = b2v; binit[3] = b2v;
#pragma unroll
        for (int et = 0; et < 4; ++et) acc2[et][nt] = binit;
    }
#pragma unroll
    for (int ks2 = 0; ks2 < 2; ++ks2) {
        U4H8 wb[4];
#pragma unroll
        for (int nt = 0; nt < 4; ++nt)
            wb[nt].u = *(const uint4*)(w2t + (size_t)(nt * 16 + n15) * 32 + ks2 * 16 + q * 4);
#pragma unroll
        for (int et = 0; et < 4; ++et) {
            unsigned tmp[4];
#pragma unroll
            for (int jr = 0; jr < 4; ++jr) {
                int srcl = (2 * (q & 1) + (jr >> 1)) * 16 + n15;
                unsigned v0 = (unsigned)__shfl((int)psrc[2 * ks2][et][jr & 1], srcl, 64);
                unsigned v1 = (unsigned)__shfl((int)psrc[2 * ks2 + 1][et][jr & 1], srcl, 64);
                tmp[jr] = (q >> 1) ? v1 : v0;
            }
            U4H8 pf;
            pf.u.x = tmp[0]; pf.u.y = tmp[1]; pf.u.z = tmp[2]; pf.u.w = tmp[3];
#pragma unroll
            for (int nt = 0; nt < 4; ++nt)
                acc2[et][nt] = __builtin_amdgcn_mfma_f32_16x16x32_f16(
                    pf.h, wb[nt].h, acc2[et][nt], 0, 0, 0);
        }
    }

    // ---- segmented reduce over edges, two column-halves through LDS ----
#pragma unroll
    for (int hf = 0; hf < 2; ++hf) {
#pragma unroll
        for (int et = 0; et < 4; ++et)
#pragma unroll
            for (int t2 = 0; t2 < 2; ++t2) {
                int nt = 2 * hf + t2;
                int cl = t2 * 16 + n15;
                int eb = et * 16 + q * 4;
#pragma unroll
                for (int r = 0; r < 4; ++r)
                    Mbuf[wid][(eb + r) * 33 + cl] = acc2[et][nt][r];
            }
        __syncthreads();
        {
            int cl = lane & 31, st = lane >> 5;
            int ebase = 32 * st;
            float run = 0.0f;
            int runkey = ckey_s[wid][ebase];
            bool atstart = true;
#pragma unroll
            for (int i = 0; i < 32; ++i) {
                int kk = ckey_s[wid][ebase + i];
                float v = Mbuf[wid][(ebase + i) * 33 + cl];
                if (kk != runkey) {
                    float* dst = agg + ((size_t)runkey << 6) + hf * 32 + cl;
                    if (atstart) atomicAdd(dst, run); else *dst = run;
                    run = 0.0f; runkey = kk; atstart = false;
                }
                run += v;
            }
            atomicAdd(agg + ((size_t)runkey << 6) + hf * 32 + cl, run);
        }
        __syncthreads();
    }
}

// MFMA upd kernel: one wave per 64 nodes; frags streamed per ks.
__global__ __launch_bounds__(64) void upd_k(
    float* __restrict__ x, unsigned* __restrict__ xh,
    const float* __restrict__ agg,
    const unsigned* __restrict__ w1t, const float* __restrict__ b1,
    const unsigned* __restrict__ w2t, const float* __restrict__ b2)
{
    __shared__ float Mbuf[64 * 33];

    const int lane = threadIdx.x;
    const int q = lane >> 4, n15 = lane & 15;
    const int nbase = blockIdx.x * 64;

    int nc[4];
#pragma unroll
    for (int nt = 0; nt < 4; ++nt) {
        int node = nbase + nt * 16 + n15;
        nc[nt] = (node < NN) ? node : (NN - 1);
    }

    f32x4 acc1[4][4];
#pragma unroll
    for (int mt = 0; mt < 4; ++mt) {
        f32x4 binit = *(const f32x4*)(b1 + mt * 16 + q * 4);
#pragma unroll
        for (int nt = 0; nt < 4; ++nt) acc1[mt][nt] = binit;
    }
#pragma unroll
    for (int ks = 0; ks < 4; ++ks) {
        U4H8 bfk[4];
#pragma unroll
        for (int nt = 0; nt < 4; ++nt) {
            if (ks < 2) {
                bfk[nt].u = ((const uint4*)(xh + ((size_t)nc[nt] << 5)))[ks * 4 + q];
            } else {
                const float4* ap = (const float4*)(agg + ((size_t)nc[nt] << 6));
                int o = (ks - 2) * 8 + 2 * q;
                float4 a0 = ap[o], a1 = ap[o + 1];
                bfk[nt].u.x = pk2(a0.x, a0.y); bfk[nt].u.y = pk2(a0.z, a0.w);
                bfk[nt].u.z = pk2(a1.x, a1.y); bfk[nt].u.w = pk2(a1.z, a1.w);
            }
        }
#pragma unroll
        for (int mt = 0; mt < 4; ++mt) {
            U4H8 af;
            af.u = *(const uint4*)(w1t + (size_t)(mt * 16 + n15) * 64 + ks * 16 + q * 4);
#pragma unroll
            for (int nt = 0; nt < 4; ++nt)
                acc1[mt][nt] = __builtin_amdgcn_mfma_f32_16x16x32_f16(
                    af.h, bfk[nt].h, acc1[mt][nt], 0, 0, 0);
        }
    }

    unsigned psrc[4][4][2];
#pragma unroll
    for (int mt = 0; mt < 4; ++mt)
#pragma unroll
        for (int nt = 0; nt < 4; ++nt) {
            psrc[mt][nt][0] = pk2(silu_f(acc1[mt][nt][0]), silu_f(acc1[mt][nt][1]));
            psrc[mt][nt][1] = pk2(silu_f(acc1[mt][nt][2]), silu_f(acc1[mt][nt][3]));
        }

    f32x4 acc2[4][4];
#pragma unroll
    for (int nt = 0; nt < 4; ++nt) {
        float b2v = b2[nt * 16 + n15];
        f32x4 binit; binit[0] = b2v; binit[1] = b2v; binit[2] = b2v; binit[3] = b2v;
#pragma unroll
        for (int et = 0; et < 4; ++et) acc2[et][nt] = binit;
    }
#pragma unroll
    for (int ks2 = 0; ks2 < 2; ++ks2) {
        U4H8 wb[4];
#pragma unroll
        for (int nt = 0; nt < 4; ++nt)
            wb[nt].u = *(const uint4*)(w2t + (size_t)(nt * 16 + n15) * 32 + ks2 * 16 + q * 4);
#pragma unroll
        for (int et = 0; et < 4; ++et) {
            unsigned tmp[4];
#pragma unroll
            for (int jr = 0; jr < 4; ++jr) {
                int srcl = (2 * (q & 1) + (jr >> 1)) * 16 + n15;
                unsigned v0 = (unsigned)__shfl((int)psrc[2 * ks2][et][jr & 1], srcl, 64);
                unsigned v1 = (unsigned)__shfl((int)psrc[2 * ks2 + 1][et][jr & 1], srcl, 64);
                tmp[jr] = (q >> 1) ? v1 : v0;
            }
            U4H8 pf;
            pf.u.x = tmp[0]; pf.u.y = tmp[1]; pf.u.z = tmp[2]; pf.u.w = tmp[3];
#pragma unroll
            for (int nt = 0; nt < 4; ++nt)
                acc2[et][nt] = __builtin_amdgcn_mfma_f32_16x16x32_f16(
                    pf.h, wb[nt].h, acc2[et][nt], 0, 0, 0);
        }
    }

#pragma unroll
    for (int hf = 0; hf < 2; ++hf) {
#pragma unroll
        for (int et = 0; et < 4; ++et)
#pragma unroll
            for (int t2 = 0; t2 < 2; ++t2) {
                int nt = 2 * hf + t2;
                int cl = t2 * 16 + n15;
                int eb = et * 16 + q * 4;
#pragma unroll
                for (int r = 0; r < 4; ++r)
                    Mbuf[(eb + r) * 33 + cl] = acc2[et][nt][r];
            }
        __syncthreads();
        {
            int node = nbase + lane;
            if (node < NN) {
                float* xr = x + ((size_t)node << 6) + hf * 32;
                unsigned* xhp = xh + ((size_t)node << 5) + hf * 16;
#pragma unroll
                for (int p = 0; p < 16; ++p) {
                    float v0 = xr[2*p]     + Mbuf[lane * 33 + 2*p];
                    float v1 = xr[2*p + 1] + Mbuf[lane * 33 + 2*p + 1];
                    xr[2*p] = v0; xr[2*p + 1] = v1;
                    xhp[p] = pk2(v0, v1);
                }
            }
        }
        __syncthreads();
    }
}

// MFMA head kernel: one wave per 64 nodes.
__global__ __launch_bounds__(64) void head_k(
    const unsigned* __restrict__ xh,
    const unsigned* __restrict__ w1t, const float* __restrict__ b1,
    const float* __restrict__ w2, const float* __restrict__ b2,
    const int* __restrict__ batch, float* __restrict__ energy)
{
    __shared__ float esum[NGRAPH];

    const int lane = threadIdx.x;
    const int q = lane >> 4, n15 = lane & 15;
    const int nbase = blockIdx.x * 64;

    esum[lane] = 0.0f;
    __syncthreads();

    int nc[4];
#pragma unroll
    for (int nt = 0; nt < 4; ++nt) {
        int node = nbase + nt * 16 + n15;
        nc[nt] = (node < NN) ? node : (NN - 1);
    }

    f32x4 acc[4][4];
#pragma unroll
    for (int mt = 0; mt < 4; ++mt) {
        f32x4 binit = *(const f32x4*)(b1 + mt * 16 + q * 4);
#pragma unroll
        for (int nt = 0; nt < 4; ++nt) acc[mt][nt] = binit;
    }
#pragma unroll
    for (int ks = 0; ks < 2; ++ks) {
        U4H8 bfk[4];
#pragma unroll
        for (int nt = 0; nt < 4; ++nt)
            bfk[nt].u = ((const uint4*)(xh + ((size_t)nc[nt] << 5)))[ks * 4 + q];
#pragma unroll
        for (int mt = 0; mt < 4; ++mt) {
            U4H8 af;
            af.u = *(const uint4*)(w1t + (size_t)(mt * 16 + n15) * 32 + ks * 16 + q * 4);
#pragma unroll
            for (int nt = 0; nt < 4; ++nt)
                acc[mt][nt] = __builtin_amdgcn_mfma_f32_16x16x32_f16(
                    af.h, bfk[nt].h, acc[mt][nt], 0, 0, 0);
        }
    }

    f32x4 wv[4];
#pragma unroll
    for (int mt = 0; mt < 4; ++mt) wv[mt] = *(const f32x4*)(w2 + mt * 16 + q * 4);
    float b2v = b2[0];
#pragma unroll
    for (int nt = 0; nt < 4; ++nt) {
        float e = 0.0f;
#pragma unroll
        for (int mt = 0; mt < 4; ++mt)
#pragma unroll
            for (int r = 0; r < 4; ++r)
                e = fmaf(silu_f(acc[mt][nt][r]), wv[mt][r], e);
        e += __shfl_xor(e, 16, 64);
        e += __shfl_xor(e, 32, 64);
        if (q == 0) {
            int node = nbase + nt * 16 + n15;
            if (node < NN) atomicAdd(&esum[batch[node]], e + b2v);
        }
    }
    __syncthreads();
    float v = esum[lane];
    if (v != 0.0f) atomicAdd(energy + lane, v);
}

extern "C" void kernel_launch(void* const* d_in, const int* in_sizes, int n_in,
                              void* d_out, int out_size, void* d_ws, size_t ws_size,
                              hipStream_t stream) {
    const int*   z       = (const int*)  d_in[0];
    const float* pos     = (const float*)d_in[1];
    const int*   eidx    = (const int*)  d_in[2];
    const int*   batch   = (const int*)  d_in[3];
    const float* embed   = (const float*)d_in[4];
    const float* msg_w1  = (const float*)d_in[5];
    const float* msg_b1  = (const float*)d_in[6];
    const float* msg_w2  = (const float*)d_in[7];
    const float* msg_b2  = (const float*)d_in[8];
    const float* upd_w1  = (const float*)d_in[9];
    const float* upd_b1  = (const float*)d_in[10];
    const float* upd_w2  = (const float*)d_in[11];
    const float* upd_b2  = (const float*)d_in[12];
    const float* eh_w1   = (const float*)d_in[13];
    const float* eh_b1   = (const float*)d_in[14];
    const float* eh_w2   = (const float*)d_in[15];
    const float* eh_b2   = (const float*)d_in[16];

    const int* erow = eidx;
    const int* ecol = eidx + EE;

    // ws layout (4-byte units); edgeS offset is 16B-aligned
    float*    x      = (float*)d_ws;                      // NN*64
    float*    agg    = x + (size_t)NN * HH;               // NN*64
    unsigned* xh     = (unsigned*)(agg + (size_t)NN * HH);// NN*32
    int*      deg    = (int*)(xh + (size_t)NN * 32);      // NN
    int*      cursor = deg + NN;                          // NN
    int*      bsum   = cursor + NN;                       // 64
    uint4*    edgeS  = (uint4*)(bsum + 64);               // EE uint4
    unsigned* w1t    = (unsigned*)(edgeS + EE);           // NL*64*80
    unsigned* w2t    = w1t + NLAYER * 64 * 80;            // NL*64*32
    unsigned* w1tu   = w2t + NLAYER * 64 * 32;            // NL*64*64
    unsigned* w2tu   = w1tu + NLAYER * 64 * 64;           // NL*64*32
    unsigned* ehw1t  = w2tu + NLAYER * 64 * 32;           // 64*32
    float*    energy = (float*)d_out;

    (void)hipMemsetAsync(energy, 0, NGRAPH * sizeof(float), stream);
    (void)hipMemsetAsync(deg, 0, NN * sizeof(int), stream);

    prep_k<<<9487, 256, 0, stream>>>(
        z, embed, x, xh,
        msg_w1, msg_w2, upd_w1, upd_w2, eh_w1,
        w1t, w2t, w1tu, w2tu, ehw1t,
        ecol, deg);

    scan1_k<<<NBLK1, 1024, 0, stream>>>(deg, cursor, bsum);
    scan2_k<<<1, 64, 0, stream>>>(bsum);
    scatter_k<<<(EE + 255) / 256, 256, 0, stream>>>(
        erow, ecol, pos, cursor, bsum, edgeS);

    for (int l = 0; l < NLAYER; ++l) {
        (void)hipMemsetAsync(agg, 0, (size_t)NN * HH * sizeof(float), stream);
        msg_k<<<EE / 256, 256, 0, stream>>>(
            edgeS, xh,
            w1t + (size_t)l * 64 * 80,
            msg_b1 + (size_t)l * HH,
            w2t + (size_t)l * 64 * 32,
            msg_b2 + (size_t)l * HH,
            agg);
        upd_k<<<(NN + 63) / 64, 64, 0, stream>>>(
            x, xh, agg,
            w1tu + (size_t)l * 64 * 64,
            upd_b1 + (size_t)l * HH,
            w2tu + (size_t)l * 64 * 32,
            upd_b2 + (size_t)l * HH);
    }

    head_k<<<(NN + 63) / 64, 64, 0, stream>>>(
        xh, ehw1t, eh_b1, eh_w2, eh_b2, batch, energy);
}

// Round 10
// 388.261 us; speedup vs baseline: 16.2087x; 1.0336x over previous
//
#include <hip/hip_runtime.h>
#include <math.h>

#define NN 50000
#define EE 800000
#define HH 64
#define NBASIS 8
#define NLAYER 2
#define NGRAPH 64
#define NBLK1 49  // ceil(NN/1024)

using half2_t = decltype(__builtin_amdgcn_cvt_pkrtz(0.0f, 0.0f));
typedef _Float16 f16x8 __attribute__((ext_vector_type(8)));
typedef float f32x4 __attribute__((ext_vector_type(4)));

union U4H8 { uint4 u; f16x8 h; };

__device__ __forceinline__ float silu_f(float v) {
    return v * (1.0f / (1.0f + __expf(-v)));
}

__device__ __forceinline__ unsigned pk2(float a, float b) {
    union { half2_t h; unsigned u; } x;
    x.h = __builtin_amdgcn_cvt_pkrtz(a, b);
    return x.u;
}

// fused prep: embed gather (blocks 0..6249), weight prepack (6250..6361),
// degree count (6362..9486)
__global__ __launch_bounds__(256) void prep_k(
    const int* __restrict__ z, const float* __restrict__ embed,
    float* __restrict__ x, unsigned* __restrict__ xh,
    const float* __restrict__ msg_w1, const float* __restrict__ msg_w2,
    const float* __restrict__ upd_w1, const float* __restrict__ upd_w2,
    const float* __restrict__ eh_w1,
    unsigned* __restrict__ w1t, unsigned* __restrict__ w2t,
    unsigned* __restrict__ w1tu, unsigned* __restrict__ w2tu,
    unsigned* __restrict__ ehw1t,
    const int* __restrict__ ecol, int* __restrict__ deg)
{
    int b = blockIdx.x;
    if (b < 6250) {                       // embed gather: NN*32 pairs
        int idx = b * 256 + threadIdx.x;  // < 1,600,000 always
        int n = idx >> 5;
        int p = idx & 31;
        const float2* er = (const float2*)(embed + ((size_t)z[n] << 6));
        float2 v = er[p];
        ((float2*)x)[idx] = v;
        xh[idx] = pk2(v.x, v.y);
    } else if (b < 6362) {                // weight prepack, 28672 threads
        int idx = (b - 6250) * 256 + threadIdx.x;
        if (idx < 10240) {                    // msg w1t [l][f 64][kp 80]
            int l = idx / 5120, rem = idx % 5120;
            int f = rem / 80, kp = rem % 80;
            const float* w = msg_w1 + (size_t)l * 136 * 64;
            unsigned v = 0;
            if (kp < 68) v = pk2(w[(2*kp)*64 + f], w[(2*kp+1)*64 + f]);
            w1t[idx] = v;
        } else if (idx < 14336) {             // msg w2t [l][n 64][kp 32]
            int j = idx - 10240;
            int l = j / 2048, rem = j % 2048;
            int n = rem / 32, kp = rem % 32;
            const float* w = msg_w2 + (size_t)l * 64 * 64;
            w2t[j] = pk2(w[(2*kp)*64 + n], w[(2*kp+1)*64 + n]);
        } else if (idx < 22528) {             // upd w1tu [l][f 64][kp 64]
            int j = idx - 14336;
            int l = j / 4096, rem = j % 4096;
            int f = rem >> 6, kp = rem & 63;
            const float* w = upd_w1 + (size_t)l * 128 * 64;
            w1tu[j] = pk2(w[(2*kp)*64 + f], w[(2*kp+1)*64 + f]);
        } else if (idx < 26624) {             // upd w2tu [l][n 64][kp 32]
            int j = idx - 22528;
            int l = j / 2048, rem = j % 2048;
            int n = rem / 32, kp = rem % 32;
            const float* w = upd_w2 + (size_t)l * 64 * 64;
            w2tu[j] = pk2(w[(2*kp)*64 + n], w[(2*kp+1)*64 + n]);
        } else if (idx < 28672) {             // head ehw1t [f 64][kp 32]
            int j = idx - 26624;
            int f = j / 32, kp = j % 32;
            ehw1t[j] = pk2(eh_w1[(2*kp)*64 + f], eh_w1[(2*kp+1)*64 + f]);
        }
    } else {                              // degree count
        int e = (b - 6362) * 256 + threadIdx.x;
        if (e < EE) atomicAdd(&deg[ecol[e]], 1);
    }
}

__global__ __launch_bounds__(1024) void scan1_k(
    const int* __restrict__ deg, int* __restrict__ cursor,
    int* __restrict__ bsum)
{
    __shared__ int wsum[16];
    int t = threadIdx.x, lane = t & 63, wave = t >> 6;
    int i = blockIdx.x * 1024 + t;
    int v = (i < NN) ? deg[i] : 0;
    int s = v;
#pragma unroll
    for (int off = 1; off < 64; off <<= 1) {
        int tv = __shfl_up(s, off, 64);
        if (lane >= off) s += tv;
    }
    if (lane == 63) wsum[wave] = s;
    __syncthreads();
    if (wave == 0) {
        int ws = (lane < 16) ? wsum[lane] : 0;
        int ss = ws;
#pragma unroll
        for (int off = 1; off < 16; off <<= 1) {
            int tv = __shfl_up(ss, off, 64);
            if (lane >= off) ss += tv;
        }
        if (lane < 16) wsum[lane] = ss - ws;
    }
    __syncthreads();
    int excl = wsum[wave] + s - v;
    if (i < NN) cursor[i] = excl;     // block-local exclusive scan
    if (t == 1023) bsum[blockIdx.x] = excl + v;
}

__global__ __launch_bounds__(64) void scan2_k(int* __restrict__ bsum)
{
    int lane = threadIdx.x;
    int v = (lane < NBLK1) ? bsum[lane] : 0;
    int s = v;
#pragma unroll
    for (int off = 1; off < 64; off <<= 1) {
        int tv = __shfl_up(s, off, 64);
        if (lane >= off) s += tv;
    }
    if (lane < NBLK1) bsum[lane] = s - v;
}

// scatter: one interleaved uint4 {row, col, d_bits, 0} per sorted slot
__global__ __launch_bounds__(256) void scatter_k(
    const int* __restrict__ erow, const int* __restrict__ ecol,
    const float* __restrict__ pos,
    int* __restrict__ cursor, const int* __restrict__ bsum,
    uint4* __restrict__ edgeS)
{
    int e = blockIdx.x * 256 + threadIdx.x;
    if (e >= EE) return;
    int c = ecol[e], r = erow[e];
    int slot = atomicAdd(&cursor[c], 1) + bsum[c >> 10];
    float dx = pos[3*r]   - pos[3*c];
    float dy = pos[3*r+1] - pos[3*c+1];
    float dz = pos[3*r+2] - pos[3*c+2];
    float d = sqrtf(dx*dx + dy*dy + dz*dz);
    uint4 v;
    v.x = (unsigned)r; v.y = (unsigned)c;
    v.z = __float_as_uint(d); v.w = 0;
    edgeS[slot] = v;
}

// MFMA msg kernel: 256-thread blocks = 4 private waves x 64 sorted edges.
__global__ __launch_bounds__(256, 4) void msg_k(
    const uint4* __restrict__ edgeS,
    const unsigned* __restrict__ xh,
    const unsigned* __restrict__ w1t, const float* __restrict__ b1,
    const unsigned* __restrict__ w2t, const float* __restrict__ b2,
    float* __restrict__ agg)
{
    __shared__ __align__(16) unsigned earr[4][64 * 4];
    __shared__ int ckey_s[4][64];
    __shared__ int rkey_s[4][64];
    __shared__ float Mbuf[4][64 * 33];

    const int wid  = threadIdx.x >> 6;
    const int lane = threadIdx.x & 63;
    const int q = lane >> 4, n15 = lane & 15;
    const size_t base = (size_t)blockIdx.x * 256 + wid * 64;

    int mykey;
    // ---- per-edge prep (single coalesced 16B read) ----
    {
        uint4 ev = edgeS[base + lane];
        rkey_s[wid][lane] = (int)ev.x;
        mykey = (int)ev.y;
        ckey_s[wid][lane] = mykey;
        float d = __uint_as_float(ev.z);
        float env = 0.0f;
        if (d < 5.0f) {
            float cv = __cosf(d * 0.31415926535897932f);  // pi/(2*CUTOFF)
            env = cv * cv;
        }
        float scale = (d > 0.0f) ? (env / d) : env;
        float ea[NBASIS];
#pragma unroll
        for (int k = 0; k < NBASIS; ++k)
            ea[k] = __sinf((float)(k + 1) * 0.62831853071795865f * d) * scale;
#pragma unroll
        for (int p = 0; p < 4; ++p)
            earr[wid][lane * 4 + p] = pk2(ea[2*p], ea[2*p+1]);
    }
    // boundary bitmask: bit L set iff key[L] != key[L-1]
    int pkk = __shfl_up(mykey, 1, 64);
    unsigned long long bmask = __ballot(lane > 0 && mykey != pkk);
    unsigned m32 = (unsigned)(bmask >> (lane & 32));  // my strip's 32 bits
    __syncthreads();

    int cn[4], rn[4];
#pragma unroll
    for (int nt = 0; nt < 4; ++nt) {
        int eB = nt * 16 + n15;
        cn[nt] = ckey_s[wid][eB];
        rn[nt] = rkey_s[wid][eB];
    }

    // ---- GEMM1, frags streamed per ks ----
    f32x4 acc1[4][4];
#pragma unroll
    for (int mt = 0; mt < 4; ++mt) {
        f32x4 binit = *(const f32x4*)(b1 + mt * 16 + q * 4);
#pragma unroll
        for (int nt = 0; nt < 4; ++nt) acc1[mt][nt] = binit;
    }
#pragma unroll
    for (int ks = 0; ks < 5; ++ks) {
        U4H8 bfk[4];
#pragma unroll
        for (int nt = 0; nt < 4; ++nt) {
            if (ks == 4) {
                uint4 zz; zz.x = zz.y = zz.z = zz.w = 0;
                bfk[nt].u = (q == 0) ? *(const uint4*)(earr[wid] + (nt * 16 + n15) * 4) : zz;
            } else if (ks < 2) {
                bfk[nt].u = ((const uint4*)(xh + ((size_t)cn[nt] << 5)))[ks * 4 + q];
            } else {
                bfk[nt].u = ((const uint4*)(xh + ((size_t)rn[nt] << 5)))[(ks - 2) * 4 + q];
            }
        }
#pragma unroll
        for (int mt = 0; mt < 4; ++mt) {
            U4H8 af;
            af.u = *(const uint4*)(w1t + (size_t)(mt * 16 + n15) * 80 + ks * 16 + q * 4);
#pragma unroll
            for (int nt = 0; nt < 4; ++nt)
                acc1[mt][nt] = __builtin_amdgcn_mfma_f32_16x16x32_f16(
                    af.h, bfk[nt].h, acc1[mt][nt], 0, 0, 0);
        }
    }

    // ---- silu + pack ----
    unsigned psrc[4][4][2];
#pragma unroll
    for (int mt = 0; mt < 4; ++mt)
#pragma unroll
        for (int nt = 0; nt < 4; ++nt) {
            psrc[mt][nt][0] = pk2(silu_f(acc1[mt][nt][0]), silu_f(acc1[mt][nt][1]));
            psrc[mt][nt][1] = pk2(silu_f(acc1[mt][nt][2]), silu_f(acc1[mt][nt][3]));
        }

    // ---- GEMM2 ----
    f32x4 acc2[4][4];
#pragma unroll
    for (int nt = 0; nt < 4; ++nt) {
        float b2v = b2[nt * 16 + n15];
        f32x4 binit; binit[0] = b2v; binit[1] = b2v; binit[2] = b2v; binit[3] = b2v;
#pragma unroll
        for (int et = 0; et < 4; ++et) acc2[et][nt] = binit;
    }
#pragma unroll
    for (int ks2 = 0; ks2 < 2; ++ks2) {
        U4H8 wb[4];
#pragma unroll
        for (int nt = 0; nt < 4; ++nt)
            wb[nt].u = *(const uint4*)(w2t + (size_t)(nt * 16 + n15) * 32 + ks2 * 16 + q * 4);
#pragma unroll
        for (int et = 0; et < 4; ++et) {
            unsigned tmp[4];
#pragma unroll
            for (int jr = 0; jr < 4; ++jr) {
                int srcl = (2 * (q & 1) + (jr >> 1)) * 16 + n15;
                unsigned v0 = (unsigned)__shfl((int)psrc[2 * ks2][et][jr & 1], srcl, 64);
                unsigned v1 = (unsigned)__shfl((int)psrc[2 * ks2 + 1][et][jr & 1], srcl, 64);
                tmp[jr] = (q >> 1) ? v1 : v0;
            }
            U4H8 pf;
            pf.u.x = tmp[0]; pf.u.y = tmp[1]; pf.u.z = tmp[2]; pf.u.w = tmp[3];
#pragma unroll
            for (int nt = 0; nt < 4; ++nt)
                acc2[et][nt] = __builtin_amdgcn_mfma_f32_16x16x32_f16(
                    pf.h, wb[nt].h, acc2[et][nt], 0, 0, 0);
        }
    }

    // ---- segmented reduce; boundary bitmask, key reads only at flips ----
#pragma unroll
    for (int hf = 0; hf < 2; ++hf) {
#pragma unroll
        for (int et = 0; et < 4; ++et)
#pragma unroll
            for (int t2 = 0; t2 < 2; ++t2) {
                int nt = 2 * hf + t2;
                int cl = t2 * 16 + n15;
                int eb = et * 16 + q * 4;
#pragma unroll
                for (int r = 0; r < 4; ++r)
                    Mbuf[wid][(eb + r) * 33 + cl] = acc2[et][nt][r];
            }
        __syncthreads();
        {
            int cl = lane & 31, st = lane >> 5;
            int ebase = 32 * st;
            float run = Mbuf[wid][ebase * 33 + cl];
            int runkey = ckey_s[wid][ebase];
            bool atstart = true;
#pragma unroll
            for (int i = 1; i < 32; ++i) {
                float v = Mbuf[wid][(ebase + i) * 33 + cl];
                if ((m32 >> i) & 1u) {
                    float* dst = agg + ((size_t)runkey << 6) + hf * 32 + cl;
                    if (atstart) atomicAdd(dst, run); else *dst = run;
                    runkey = ckey_s[wid][ebase + i]; atstart = false;
                    run = v;
                } else {
                    run += v;
                }
            }
            atomicAdd(agg + ((size_t)runkey << 6) + hf * 32 + cl, run);
        }
        __syncthreads();
    }
}

// MFMA upd kernel: one wave per 64 nodes; optional fused head + agg rezero.
__global__ __launch_bounds__(64) void upd_k(
    float* __restrict__ x, unsigned* __restrict__ xh,
    float* __restrict__ agg,
    const unsigned* __restrict__ w1t, const float* __restrict__ b1,
    const unsigned* __restrict__ w2t, const float* __restrict__ b2,
    const unsigned* __restrict__ ehw1t, const float* __restrict__ ehb1,
    const float* __restrict__ ehw2, const float* __restrict__ ehb2,
    const int* __restrict__ batch, float* __restrict__ energy,
    int do_zero, int do_head)
{
    __shared__ float Mbuf[64 * 33];
    __shared__ float esum[NGRAPH];

    const int lane = threadIdx.x;
    const int q = lane >> 4, n15 = lane & 15;
    const int nbase = blockIdx.x * 64;

    int nc[4];
#pragma unroll
    for (int nt = 0; nt < 4; ++nt) {
        int node = nbase + nt * 16 + n15;
        nc[nt] = (node < NN) ? node : (NN - 1);
    }

    f32x4 acc1[4][4];
#pragma unroll
    for (int mt = 0; mt < 4; ++mt) {
        f32x4 binit = *(const f32x4*)(b1 + mt * 16 + q * 4);
#pragma unroll
        for (int nt = 0; nt < 4; ++nt) acc1[mt][nt] = binit;
    }
#pragma unroll
    for (int ks = 0; ks < 4; ++ks) {
        U4H8 bfk[4];
#pragma unroll
        for (int nt = 0; nt < 4; ++nt) {
            if (ks < 2) {
                bfk[nt].u = ((const uint4*)(xh + ((size_t)nc[nt] << 5)))[ks * 4 + q];
            } else {
                const float4* ap = (const float4*)(agg + ((size_t)nc[nt] << 6));
                int o = (ks - 2) * 8 + 2 * q;
                float4 a0 = ap[o], a1 = ap[o + 1];
                bfk[nt].u.x = pk2(a0.x, a0.y); bfk[nt].u.y = pk2(a0.z, a0.w);
                bfk[nt].u.z = pk2(a1.x, a1.y); bfk[nt].u.w = pk2(a1.z, a1.w);
            }
        }
#pragma unroll
        for (int mt = 0; mt < 4; ++mt) {
            U4H8 af;
            af.u = *(const uint4*)(w1t + (size_t)(mt * 16 + n15) * 64 + ks * 16 + q * 4);
#pragma unroll
            for (int nt = 0; nt < 4; ++nt)
                acc1[mt][nt] = __builtin_amdgcn_mfma_f32_16x16x32_f16(
                    af.h, bfk[nt].h, acc1[mt][nt], 0, 0, 0);
        }
    }

    unsigned psrc[4][4][2];
#pragma unroll
    for (int mt = 0; mt < 4; ++mt)
#pragma unroll
        for (int nt = 0; nt < 4; ++nt) {
            psrc[mt][nt][0] = pk2(silu_f(acc1[mt][nt][0]), silu_f(acc1[mt][nt][1]));
            psrc[mt][nt][1] = pk2(silu_f(acc1[mt][nt][2]), silu_f(acc1[mt][nt][3]));
        }

    f32x4 acc2[4][4];
#pragma unroll
    for (int nt = 0; nt < 4; ++nt) {
        float b2v = b2[nt * 16 + n15];
        f32x4 binit; binit[0] = b2v; binit[1] = b2v; binit[2] = b2v; binit[3] = b2v;
#pragma unroll
        for (int et = 0; et < 4; ++et) acc2[et][nt] = binit;
    }
#pragma unroll
    for (int ks2 = 0; ks2 < 2; ++ks2) {
        U4H8 wb[4];
#pragma unroll
        for (int nt = 0; nt < 4; ++nt)
            wb[nt].u = *(const uint4*)(w2t + (size_t)(nt * 16 + n15) * 32 + ks2 * 16 + q * 4);
#pragma unroll
        for (int et = 0; et < 4; ++et) {
            unsigned tmp[4];
#pragma unroll
            for (int jr = 0; jr < 4; ++jr) {
                int srcl = (2 * (q & 1) + (jr >> 1)) * 16 + n15;
                unsigned v0 = (unsigned)__shfl((int)psrc[2 * ks2][et][jr & 1], srcl, 64);
                unsigned v1 = (unsigned)__shfl((int)psrc[2 * ks2 + 1][et][jr & 1], srcl, 64);
                tmp[jr] = (q >> 1) ? v1 : v0;
            }
            U4H8 pf;
            pf.u.x = tmp[0]; pf.u.y = tmp[1]; pf.u.z = tmp[2]; pf.u.w = tmp[3];
#pragma unroll
            for (int nt = 0; nt < 4; ++nt)
                acc2[et][nt] = __builtin_amdgcn_mfma_f32_16x16x32_f16(
                    pf.h, wb[nt].h, acc2[et][nt], 0, 0, 0);
        }
    }

    // ---- epilogue: x += out, refresh xh; keep final pairs for head ----
    unsigned prr[32];
#pragma unroll
    for (int p = 0; p < 32; ++p) prr[p] = 0;
#pragma unroll
    for (int hf = 0; hf < 2; ++hf) {
#pragma unroll
        for (int et = 0; et < 4; ++et)
#pragma unroll
            for (int t2 = 0; t2 < 2; ++t2) {
                int nt = 2 * hf + t2;
                int cl = t2 * 16 + n15;
                int eb = et * 16 + q * 4;
#pragma unroll
                for (int r = 0; r < 4; ++r)
                    Mbuf[(eb + r) * 33 + cl] = acc2[et][nt][r];
            }
        __syncthreads();
        {
            int node = nbase + lane;
            if (node < NN) {
                float* xr = x + ((size_t)node << 6) + hf * 32;
                unsigned* xhp = xh + ((size_t)node << 5) + hf * 16;
#pragma unroll
                for (int p = 0; p < 16; ++p) {
                    float v0 = xr[2*p]     + Mbuf[lane * 33 + 2*p];
                    float v1 = xr[2*p + 1] + Mbuf[lane * 33 + 2*p + 1];
                    xr[2*p] = v0; xr[2*p + 1] = v1;
                    unsigned pv = pk2(v0, v1);
                    xhp[p] = pv;
                    prr[hf * 16 + p] = pv;
                }
            }
        }
        __syncthreads();
    }

    if (do_zero) {   // pre-zero agg for the next layer's msg accumulation
        int node = nbase + lane;
        if (node < NN) {
            float4 z4; z4.x = z4.y = z4.z = z4.w = 0.0f;
            float4* ap = (float4*)(agg + ((size_t)node << 6));
#pragma unroll
            for (int p = 0; p < 16; ++p) ap[p] = z4;
        }
    }

    if (do_head) {
        // stage final f16 pairs via Mbuf (reused as unsigned)
        unsigned* MU = (unsigned*)Mbuf;
        esum[lane] = 0.0f;
#pragma unroll
        for (int p = 0; p < 32; ++p) MU[lane * 33 + p] = prr[p];
        __syncthreads();

        f32x4 acch[4][4];
#pragma unroll
        for (int mt = 0; mt < 4; ++mt) {
            f32x4 binit = *(const f32x4*)(ehb1 + mt * 16 + q * 4);
#pragma unroll
            for (int nt = 0; nt < 4; ++nt) acch[mt][nt] = binit;
        }
#pragma unroll
        for (int ks = 0; ks < 2; ++ks) {
            U4H8 bfk[4];
#pragma unroll
            for (int nt = 0; nt < 4; ++nt) {
                int nd = nt * 16 + n15;
                bfk[nt].u.x = MU[nd * 33 + ks * 16 + 4 * q + 0];
                bfk[nt].u.y = MU[nd * 33 + ks * 16 + 4 * q + 1];
                bfk[nt].u.z = MU[nd * 33 + ks * 16 + 4 * q + 2];
                bfk[nt].u.w = MU[nd * 33 + ks * 16 + 4 * q + 3];
            }
#pragma unroll
            for (int mt = 0; mt < 4; ++mt) {
                U4H8 af;
                af.u = *(const uint4*)(ehw1t + (size_t)(mt * 16 + n15) * 32 + ks * 16 + q * 4);
#pragma unroll
                for (int nt = 0; nt < 4; ++nt)
                    acch[mt][nt] = __builtin_amdgcn_mfma_f32_16x16x32_f16(
                        af.h, bfk[nt].h, acch[mt][nt], 0, 0, 0);
            }
        }

        f32x4 wv[4];
#pragma unroll
        for (int mt = 0; mt < 4; ++mt) wv[mt] = *(const f32x4*)(ehw2 + mt * 16 + q * 4);
        float b2v = ehb2[0];
#pragma unroll
        for (int nt = 0; nt < 4; ++nt) {
            float e = 0.0f;
#pragma unroll
            for (int mt = 0; mt < 4; ++mt)
#pragma unroll
                for (int r = 0; r < 4; ++r)
                    e = fmaf(silu_f(acch[mt][nt][r]), wv[mt][r], e);
            e += __shfl_xor(e, 16, 64);
            e += __shfl_xor(e, 32, 64);
            if (q == 0) {
                int node = nbase + nt * 16 + n15;
                if (node < NN) atomicAdd(&esum[batch[node]], e + b2v);
            }
        }
        __syncthreads();
        float v = esum[lane];
        if (v != 0.0f) atomicAdd(energy + lane, v);
    }
}

extern "C" void kernel_launch(void* const* d_in, const int* in_sizes, int n_in,
                              void* d_out, int out_size, void* d_ws, size_t ws_size,
                              hipStream_t stream) {
    const int*   z       = (const int*)  d_in[0];
    const float* pos     = (const float*)d_in[1];
    const int*   eidx    = (const int*)  d_in[2];
    const int*   batch   = (const int*)  d_in[3];
    const float* embed   = (const float*)d_in[4];
    const float* msg_w1  = (const float*)d_in[5];
    const float* msg_b1  = (const float*)d_in[6];
    const float* msg_w2  = (const float*)d_in[7];
    const float* msg_b2  = (const float*)d_in[8];
    const float* upd_w1  = (const float*)d_in[9];
    const float* upd_b1  = (const float*)d_in[10];
    const float* upd_w2  = (const float*)d_in[11];
    const float* upd_b2  = (const float*)d_in[12];
    const float* eh_w1   = (const float*)d_in[13];
    const float* eh_b1   = (const float*)d_in[14];
    const float* eh_w2   = (const float*)d_in[15];
    const float* eh_b2   = (const float*)d_in[16];

    const int* erow = eidx;
    const int* ecol = eidx + EE;

    // ws layout (4-byte units); edgeS offset is 16B-aligned
    float*    x      = (float*)d_ws;                      // NN*64
    float*    agg    = x + (size_t)NN * HH;               // NN*64
    unsigned* xh     = (unsigned*)(agg + (size_t)NN * HH);// NN*32
    int*      deg    = (int*)(xh + (size_t)NN * 32);      // NN
    int*      cursor = deg + NN;                          // NN
    int*      bsum   = cursor + NN;                       // 64
    uint4*    edgeS  = (uint4*)(bsum + 64);               // EE uint4
    unsigned* w1t    = (unsigned*)(edgeS + EE);           // NL*64*80
    unsigned* w2t    = w1t + NLAYER * 64 * 80;            // NL*64*32
    unsigned* w1tu   = w2t + NLAYER * 64 * 32;            // NL*64*64
    unsigned* w2tu   = w1tu + NLAYER * 64 * 64;           // NL*64*32
    unsigned* ehw1t  = w2tu + NLAYER * 64 * 32;           // 64*32
    float*    energy = (float*)d_out;

    (void)hipMemsetAsync(energy, 0, NGRAPH * sizeof(float), stream);
    (void)hipMemsetAsync(deg, 0, NN * sizeof(int), stream);
    (void)hipMemsetAsync(agg, 0, (size_t)NN * HH * sizeof(float), stream);

    prep_k<<<9487, 256, 0, stream>>>(
        z, embed, x, xh,
        msg_w1, msg_w2, upd_w1, upd_w2, eh_w1,
        w1t, w2t, w1tu, w2tu, ehw1t,
        ecol, deg);

    scan1_k<<<NBLK1, 1024, 0, stream>>>(deg, cursor, bsum);
    scan2_k<<<1, 64, 0, stream>>>(bsum);
    scatter_k<<<(EE + 255) / 256, 256, 0, stream>>>(
        erow, ecol, pos, cursor, bsum, edgeS);

    for (int l = 0; l < NLAYER; ++l) {
        msg_k<<<EE / 256, 256, 0, stream>>>(
            edgeS, xh,
            w1t + (size_t)l * 64 * 80,
            msg_b1 + (size_t)l * HH,
            w2t + (size_t)l * 64 * 32,
            msg_b2 + (size_t)l * HH,
            agg);
        upd_k<<<(NN + 63) / 64, 64, 0, stream>>>(
            x, xh, agg,
            w1tu + (size_t)l * 64 * 64,
            upd_b1 + (size_t)l * HH,
            w2tu + (size_t)l * 64 * 32,
            upd_b2 + (size_t)l * HH,
            ehw1t, eh_b1, eh_w2, eh_b2, batch, energy,
            (l == 0) ? 1 : 0,            // re-zero agg for next layer
            (l == NLAYER - 1) ? 1 : 0);  // fused head on last layer
    }
}